// Round 12
// baseline (3253.614 us; speedup 1.0000x reference)
//
#include <hip/hip_runtime.h>
#include <hip/hip_bf16.h>

// Problem dims (fixed by setup_inputs)
constexpr int kNS = 16384;   // support rows
constexpr int kNQ = 8192;    // query rows
constexpr int kD  = 256;     // feature dim
constexpr int kC  = 64;      // classes

// RESOLVED (R11 discriminator): inputs fp32, labels int32, OUTPUTS FLOAT32
// (not bf16!). Every round executed; R2-R10's "exact 4.468750" was Output 0's
// tail reading harness zeros because bf16 u16 writes covered only half the
// f32 output buffer. R11's +1024 magic read back as 1028.34 inside Output 0
// (two bf16(1024) halves = f32 bits 0x44xx44xx) - proving f32 layout.

// ---------------- workspace layout (float offsets into d_ws), ~11.8 MB ----
constexpr size_t OFF_PSUM  = 0;
constexpr size_t OFF_PCNT  = 16384;
constexpr size_t OFF_MUSUM = 16448;
constexpr size_t OFF_XTX   = 16704;
constexpr size_t OFF_HIST  = 82240;
constexpr size_t OFF_SSUM  = 84288;
constexpr size_t ZERO_FLOATS = 84352;
constexpr size_t OFF_PROTO = 84352;
constexpr size_t OFF_MU    = 100736;
constexpr size_t OFF_COV   = 100992;
constexpr size_t OFF_ROWS  = 166528;
constexpr size_t OFF_C     = 166784;
constexpr size_t OFF_Y     = 166800;
constexpr size_t OFF_Z     = 232336;
constexpr size_t OFF_T     = 297872;
constexpr size_t OFF_Y2    = 363408;
constexpr size_t OFF_Z2    = 428944;
constexpr size_t OFF_M     = 494480;
constexpr size_t OFF_S2    = 560016;
constexpr size_t OFF_Q2P   = 576400;
constexpr size_t OFF_PART  = 584592;
constexpr size_t OFF_G     = 846736;

__device__ __forceinline__ float waveReduceSum(float v) {
#pragma unroll
  for (int off = 32; off > 0; off >>= 1) v += __shfl_xor(v, off);
  return v;
}
__device__ __forceinline__ float waveReduceMax(float v) {
#pragma unroll
  for (int off = 32; off > 0; off >>= 1) v = fmaxf(v, __shfl_xor(v, off));
  return v;
}
__device__ __forceinline__ void fma16(float acc[4][4], float4 a, float4 b) {
  acc[0][0] += a.x*b.x; acc[0][1] += a.x*b.y; acc[0][2] += a.x*b.z; acc[0][3] += a.x*b.w;
  acc[1][0] += a.y*b.x; acc[1][1] += a.y*b.y; acc[1][2] += a.y*b.z; acc[1][3] += a.y*b.w;
  acc[2][0] += a.z*b.x; acc[2][1] += a.z*b.y; acc[2][2] += a.z*b.z; acc[2][3] += a.z*b.w;
  acc[3][0] += a.w*b.x; acc[3][1] += a.w*b.y; acc[3][2] += a.w*b.z; acc[3][3] += a.w*b.w;
}

__global__ void k_zero_r12(float* __restrict__ ws) {
  size_t i = (size_t)blockIdx.x * 256 + threadIdx.x;
  if (i < ZERO_FLOATS) ws[i] = 0.f;
}

// ---------------- classification path ----------------
__global__ void k_proto_accum_r12(const float* __restrict__ X, const int* __restrict__ lab,
                                  float* __restrict__ psum, float* __restrict__ pcnt) {
  int w = threadIdx.x >> 6, lane = threadIdx.x & 63;
  int row = blockIdx.x * 4 + w;
  float4 v = *(const float4*)&X[(size_t)row * kD + lane * 4];
  float ss = waveReduceSum(v.x*v.x + v.y*v.y + v.z*v.z + v.w*v.w);
  float inv = 1.0f / fmaxf(sqrtf(ss), 1e-8f);
  int l = lab[row];
  float* p = psum + (size_t)l * kD + lane * 4;
  atomicAdd(p + 0, v.x * inv); atomicAdd(p + 1, v.y * inv);
  atomicAdd(p + 2, v.z * inv); atomicAdd(p + 3, v.w * inv);
  if (lane == 0) atomicAdd(&pcnt[l], 1.0f);
}

__global__ void k_proto_fin_r12(const float* __restrict__ psum, const float* __restrict__ pcnt,
                                float* __restrict__ protos) {
  int c = blockIdx.x, lane = threadIdx.x;
  float4 v = *(const float4*)&psum[(size_t)c * kD + lane * 4];
  float cnt = fmaxf(pcnt[c], 1.0f);
  v.x /= cnt; v.y /= cnt; v.z /= cnt; v.w /= cnt;
  float ss = waveReduceSum(v.x*v.x + v.y*v.y + v.z*v.z + v.w*v.w);
  float inv = 1.0f / fmaxf(sqrtf(ss), 1e-8f);
  float4 o = {v.x*inv, v.y*inv, v.z*inv, v.w*inv};
  *(float4*)&protos[(size_t)c * kD + lane * 4] = o;
}

// one block (4 waves) per query: 64 dots + log_softmax, f32 out
__global__ void k_logits_r12(const float* __restrict__ Q, const float* __restrict__ protos,
                             float* __restrict__ out0) {
  __shared__ alignas(16) float qs[kD];
  __shared__ float lg[kC];
  __shared__ float wred[4];
  __shared__ float qis;
  int t = threadIdx.x, w = t >> 6, lane = t & 63;
  int qi = blockIdx.x;
  float myv = Q[(size_t)qi * kD + t];
  qs[t] = myv;
  float ss = waveReduceSum(myv * myv);
  if (lane == 0) wred[w] = ss;
  __syncthreads();
  if (t == 0) qis = 1.0f / fmaxf(sqrtf(wred[0] + wred[1] + wred[2] + wred[3]), 1e-8f);
  __syncthreads();
  float4 qv = *(const float4*)&qs[lane * 4];
  for (int cc = w * 16; cc < w * 16 + 16; ++cc) {
    float4 pv = *(const float4*)&protos[(size_t)cc * kD + lane * 4];
    float d = waveReduceSum(qv.x*pv.x + qv.y*pv.y + qv.z*pv.z + qv.w*pv.w);
    if (lane == 0) lg[cc] = d * qis;
  }
  __syncthreads();
  if (t < 64) {
    float v = lg[t];
    float m = waveReduceMax(v);
    float e = expf(v - m);
    float s = waveReduceSum(e);
    float lse = m + logf(s);
    out0[(size_t)qi * kC + t] = v - lse;
  }
}

// ---------------- regression path ----------------
__global__ void k_colsum_r12(const float* __restrict__ X, float* __restrict__ musum) {
  int t = threadIdx.x;
  int r0 = blockIdx.x * 256;
  float s = 0.f;
  for (int r = 0; r < 256; ++r) s += X[(size_t)(r0 + r) * kD + t];
  atomicAdd(&musum[t], s);
}
__global__ void k_mufin_r12(const float* __restrict__ musum, float* __restrict__ mu) {
  int t = threadIdx.x;
  mu[t] = musum[t] * (1.0f / (float)kNS);
}

__global__ void k_xtx_r12(const float* __restrict__ X, float* __restrict__ xtx) {
  __shared__ alignas(16) float As[16][68];
  __shared__ alignas(16) float Bs[16][68];
  int t = threadIdx.x, tx = t & 15, ty = t >> 4;
  int ab = (blockIdx.x >> 2) * 64, bb = (blockIdx.x & 3) * 64;
  int k0b = blockIdx.y * 1024;
  float acc[4][4] = {};
  for (int k0 = 0; k0 < 1024; k0 += 16) {
    __syncthreads();
    int j = t & 63, kr0 = t >> 6;
#pragma unroll
    for (int p = 0; p < 4; ++p) {
      int kr = kr0 + p * 4;
      size_t base = (size_t)(k0b + k0 + kr) * kD;
      As[kr][j] = X[base + ab + j];
      Bs[kr][j] = X[base + bb + j];
    }
    __syncthreads();
#pragma unroll
    for (int k = 0; k < 16; ++k) {
      float4 a = *(const float4*)&As[k][ty * 4];
      float4 b = *(const float4*)&Bs[k][tx * 4];
      fma16(acc, a, b);
    }
  }
#pragma unroll
  for (int r = 0; r < 4; ++r)
#pragma unroll
    for (int c = 0; c < 4; ++c)
      atomicAdd(&xtx[(size_t)(ab + ty * 4 + r) * kD + bb + tx * 4 + c], acc[r][c]);
}

__global__ void k_cov_r12(const float* __restrict__ xtx, const float* __restrict__ mu,
                          float* __restrict__ cov) {
  int i = blockIdx.x, j = threadIdx.x;
  float v = (xtx[(size_t)i * kD + j] - (float)kNS * mu[i] * mu[j]) * (1.0f / (float)(kNS - 1));
  if (i == j) v += 1e-4f;
  cov[(size_t)i * kD + j] = v;
}

__global__ void k_rowabs_r12(const float* __restrict__ cov, float* __restrict__ rows) {
  int row = blockIdx.x, lane = threadIdx.x;
  float4 v = *(const float4*)&cov[(size_t)row * kD + lane * 4];
  float s = waveReduceSum(fabsf(v.x) + fabsf(v.y) + fabsf(v.z) + fabsf(v.w));
  if (lane == 0) rows[row] = s;
}
__global__ void k_cnorm_r12(const float* __restrict__ rows, float* __restrict__ cptr) {
  int lane = threadIdx.x;
  float m = fmaxf(fmaxf(rows[lane], rows[lane + 64]),
                  fmaxf(rows[lane + 128], rows[lane + 192]));
  m = waveReduceMax(m);
  if (lane == 0) cptr[0] = m;
}
__global__ void k_nsinit_r12(const float* __restrict__ cov, const float* __restrict__ cptr,
                             float* __restrict__ Y, float* __restrict__ Z) {
  int i = blockIdx.x, j = threadIdx.x;
  float invc = 1.0f / cptr[0];
  size_t idx = (size_t)i * kD + j;
  Y[idx] = cov[idx] * invc;
  Z[idx] = (i == j) ? 1.0f : 0.0f;
}

// T = 1.5 I - 0.5 * (Z @ Y)
__global__ void k_ns_t_r12(const float* __restrict__ Zc, const float* __restrict__ Yc,
                           float* __restrict__ T) {
  __shared__ alignas(16) float As[16][68];
  __shared__ alignas(16) float Bs[16][68];
  int t = threadIdx.x, tx = t & 15, ty = t >> 4;
  int mb = (blockIdx.x >> 2) * 64, nb = (blockIdx.x & 3) * 64;
  float acc[4][4] = {};
  for (int k0 = 0; k0 < 256; k0 += 16) {
    __syncthreads();
    {
      int kk = t & 15, m0 = t >> 4;
#pragma unroll
      for (int p = 0; p < 4; ++p) {
        int m = m0 + p * 16;
        As[kk][m] = Zc[(size_t)(mb + m) * kD + k0 + kk];
      }
      int j = t & 63, kr0 = t >> 6;
#pragma unroll
      for (int p = 0; p < 4; ++p) {
        int kr = kr0 + p * 4;
        Bs[kr][j] = Yc[(size_t)(k0 + kr) * kD + nb + j];
      }
    }
    __syncthreads();
#pragma unroll
    for (int k = 0; k < 16; ++k) {
      float4 a = *(const float4*)&As[k][ty * 4];
      float4 b = *(const float4*)&Bs[k][tx * 4];
      fma16(acc, a, b);
    }
  }
#pragma unroll
  for (int r = 0; r < 4; ++r)
#pragma unroll
    for (int c = 0; c < 4; ++c) {
      int gi = mb + ty * 4 + r, gj = nb + tx * 4 + c;
      T[(size_t)gi * kD + gj] = (gi == gj ? 1.5f : 0.0f) - 0.5f * acc[r][c];
    }
}

// blockIdx.y==0: Yn = Yc @ T ; blockIdx.y==1: Zn = T @ Zc
__global__ void k_ns_yz_r12(const float* __restrict__ Yc, const float* __restrict__ Zc,
                            const float* __restrict__ T, float* __restrict__ Yn,
                            float* __restrict__ Zn) {
  const float* A; const float* B; float* O;
  if (blockIdx.y == 0) { A = Yc; B = T; O = Yn; } else { A = T; B = Zc; O = Zn; }
  __shared__ alignas(16) float As[16][68];
  __shared__ alignas(16) float Bs[16][68];
  int t = threadIdx.x, tx = t & 15, ty = t >> 4;
  int mb = (blockIdx.x >> 2) * 64, nb = (blockIdx.x & 3) * 64;
  float acc[4][4] = {};
  for (int k0 = 0; k0 < 256; k0 += 16) {
    __syncthreads();
    {
      int kk = t & 15, m0 = t >> 4;
#pragma unroll
      for (int p = 0; p < 4; ++p) {
        int m = m0 + p * 16;
        As[kk][m] = A[(size_t)(mb + m) * kD + k0 + kk];
      }
      int j = t & 63, kr0 = t >> 6;
#pragma unroll
      for (int p = 0; p < 4; ++p) {
        int kr = kr0 + p * 4;
        Bs[kr][j] = B[(size_t)(k0 + kr) * kD + nb + j];
      }
    }
    __syncthreads();
#pragma unroll
    for (int k = 0; k < 16; ++k) {
      float4 a = *(const float4*)&As[k][ty * 4];
      float4 b = *(const float4*)&Bs[k][tx * 4];
      fma16(acc, a, b);
    }
  }
#pragma unroll
  for (int r = 0; r < 4; ++r) {
    int gi = mb + ty * 4 + r;
    float4 o = {acc[r][0], acc[r][1], acc[r][2], acc[r][3]};
    *(float4*)&O[(size_t)gi * kD + nb + tx * 4] = o;
  }
}

// M = Zf @ Zf / c   (cov^-1, since Zf = (cov/c)^(-1/2))
__global__ void k_msq_r12(const float* __restrict__ Zf, const float* __restrict__ cptr,
                          float* __restrict__ M) {
  __shared__ alignas(16) float As[16][68];
  __shared__ alignas(16) float Bs[16][68];
  int t = threadIdx.x, tx = t & 15, ty = t >> 4;
  int mb = (blockIdx.x >> 2) * 64, nb = (blockIdx.x & 3) * 64;
  float acc[4][4] = {};
  for (int k0 = 0; k0 < 256; k0 += 16) {
    __syncthreads();
    {
      int kk = t & 15, m0 = t >> 4;
#pragma unroll
      for (int p = 0; p < 4; ++p) {
        int m = m0 + p * 16;
        As[kk][m] = Zf[(size_t)(mb + m) * kD + k0 + kk];
      }
      int j = t & 63, kr0 = t >> 6;
#pragma unroll
      for (int p = 0; p < 4; ++p) {
        int kr = kr0 + p * 4;
        Bs[kr][j] = Zf[(size_t)(k0 + kr) * kD + nb + j];
      }
    }
    __syncthreads();
#pragma unroll
    for (int k = 0; k < 16; ++k) {
      float4 a = *(const float4*)&As[k][ty * 4];
      float4 b = *(const float4*)&Bs[k][tx * 4];
      fma16(acc, a, b);
    }
  }
  float invc = 1.0f / cptr[0];
#pragma unroll
  for (int r = 0; r < 4; ++r) {
    int gi = mb + ty * 4 + r;
    float4 o = {acc[r][0] * invc, acc[r][1] * invc, acc[r][2] * invc, acc[r][3] * invc};
    *(float4*)&M[(size_t)gi * kD + nb + tx * 4] = o;
  }
}

// G = (Q - mu) @ M   [kNQ x kD]
__global__ void k_G_r12(const float* __restrict__ Q, const float* __restrict__ mu,
                        const float* __restrict__ M, float* __restrict__ G) {
  __shared__ alignas(16) float As[16][68];
  __shared__ alignas(16) float Bs[16][68];
  int t = threadIdx.x, tx = t & 15, ty = t >> 4;
  int nb = blockIdx.x * 64;
  int mb = blockIdx.y * 64;
  float acc[4][4] = {};
  for (int k0 = 0; k0 < 256; k0 += 16) {
    __syncthreads();
    {
      int kk = t & 15, m0 = t >> 4;
      float muk = mu[k0 + kk];
#pragma unroll
      for (int p = 0; p < 4; ++p) {
        int m = m0 + p * 16;
        As[kk][m] = Q[(size_t)(mb + m) * kD + k0 + kk] - muk;
      }
      int j = t & 63, kr0 = t >> 6;
#pragma unroll
      for (int p = 0; p < 4; ++p) {
        int kr = kr0 + p * 4;
        Bs[kr][j] = M[(size_t)(k0 + kr) * kD + nb + j];
      }
    }
    __syncthreads();
#pragma unroll
    for (int k = 0; k < 16; ++k) {
      float4 a = *(const float4*)&As[k][ty * 4];
      float4 b = *(const float4*)&Bs[k][tx * 4];
      fma16(acc, a, b);
    }
  }
#pragma unroll
  for (int r = 0; r < 4; ++r) {
    int gi = mb + ty * 4 + r;
    float4 o = {acc[r][0], acc[r][1], acc[r][2], acc[r][3]};
    *(float4*)&G[(size_t)gi * kD + nb + tx * 4] = o;
  }
}

// q2p[i] = G_i . (Q_i + mu)
__global__ void k_q2p_r12(const float* __restrict__ G, const float* __restrict__ Q,
                          const float* __restrict__ mu, float* __restrict__ q2p) {
  int w = threadIdx.x >> 6, lane = threadIdx.x & 63;
  int row = blockIdx.x * 4 + w;
  float4 g = *(const float4*)&G[(size_t)row * kD + lane * 4];
  float4 q = *(const float4*)&Q[(size_t)row * kD + lane * 4];
  float4 m = *(const float4*)&mu[lane * 4];
  float ss = waveReduceSum(g.x*(q.x+m.x) + g.y*(q.y+m.y) + g.z*(q.z+m.z) + g.w*(q.w+m.w));
  if (lane == 0) q2p[row] = ss;
}

// s2[j] = (S_j - mu) M (S_j - mu), per 64-row chunk
__global__ void k_s2_r12(const float* __restrict__ S, const float* __restrict__ mu,
                         const float* __restrict__ M, float* __restrict__ s2) {
  __shared__ alignas(16) float As[16][68];
  __shared__ alignas(16) float Bs[16][68];
  __shared__ float red[64][17];
  int t = threadIdx.x, tx = t & 15, ty = t >> 4;
  int mb = blockIdx.x * 64;
  float partial[4] = {0.f, 0.f, 0.f, 0.f};
  for (int ntile = 0; ntile < 4; ++ntile) {
    int nb = ntile * 64;
    float acc[4][4] = {};
    for (int k0 = 0; k0 < 256; k0 += 16) {
      __syncthreads();
      {
        int kk = t & 15, m0 = t >> 4;
        float muk = mu[k0 + kk];
#pragma unroll
        for (int p = 0; p < 4; ++p) {
          int m = m0 + p * 16;
          As[kk][m] = S[(size_t)(mb + m) * kD + k0 + kk] - muk;
        }
        int j = t & 63, kr0 = t >> 6;
#pragma unroll
        for (int p = 0; p < 4; ++p) {
          int kr = kr0 + p * 4;
          Bs[kr][j] = M[(size_t)(k0 + kr) * kD + nb + j];
        }
      }
      __syncthreads();
#pragma unroll
      for (int k = 0; k < 16; ++k) {
        float4 a = *(const float4*)&As[k][ty * 4];
        float4 b = *(const float4*)&Bs[k][tx * 4];
        fma16(acc, a, b);
      }
    }
#pragma unroll
    for (int r = 0; r < 4; ++r) {
      int gi = mb + ty * 4 + r;
#pragma unroll
      for (int c = 0; c < 4; ++c) {
        int gj = nb + tx * 4 + c;
        partial[r] += acc[r][c] * (S[(size_t)gi * kD + gj] - mu[gj]);
      }
    }
  }
  __syncthreads();
#pragma unroll
  for (int r = 0; r < 4; ++r) red[ty * 4 + r][tx] = partial[r];
  __syncthreads();
  if (t < 64) {
    float s = 0.f;
#pragma unroll
    for (int x = 0; x < 16; ++x) s += red[t][x];
    s2[mb + t] = s;
  }
}

// sampled (stride 8 x stride 8) d2 histogram for the median
__global__ void k_median_r12(const float* __restrict__ G, const float* __restrict__ S,
                             const float* __restrict__ q2p, const float* __restrict__ s2,
                             unsigned int* __restrict__ hist, float* __restrict__ ssum) {
  __shared__ unsigned int h[2048];
  int t = threadIdx.x, w = t >> 6, lane = t & 63;
  for (int i = t; i < 2048; i += 256) h[i] = 0u;
  __syncthreads();
  int qi = (blockIdx.x * 4 + w) * 8;
  float4 gv = *(const float4*)&G[(size_t)qi * kD + lane * 4];
  float q2v = q2p[qi];
  float fsum = 0.f;
  for (int b = 0; b < 2048; ++b) {
    int sj = b * 8;
    float4 sv = *(const float4*)&S[(size_t)sj * kD + lane * 4];
    float p = waveReduceSum(gv.x*sv.x + gv.y*sv.y + gv.z*sv.z + gv.w*sv.w);
    if (lane == 0) {
      float d2 = fmaxf(q2v + s2[sj] - 2.0f * p, 0.0f);
      fsum += d2;
      int bin = (int)(d2 * 2.0f);
      bin = bin > 2047 ? 2047 : bin;
      atomicAdd(&h[bin], 1u);
    }
  }
  if (lane == 0) atomicAdd(ssum, fsum);
  __syncthreads();
  for (int i = t; i < 2048; i += 256)
    if (h[i]) atomicAdd(&hist[i], h[i]);
}

__global__ void k_gamma_r12(const unsigned int* __restrict__ hist,
                            const float* __restrict__ ssum, float* __restrict__ gptr) {
  if (threadIdx.x != 0) return;
  unsigned long long total = 0;
  for (int i = 0; i < 2048; ++i) total += (unsigned long long)hist[i];
  unsigned long long rr0 = (total - 1) / 2, rr1 = total / 2;
  float v0 = 0.f, v1 = 0.f;
  bool f0 = false, f1 = false;
  unsigned long long cum = 0;
  for (int i = 0; i < 2048; ++i) {
    unsigned int c = hist[i];
    if (!f0 && c > 0 && cum + c > rr0) {
      float frac = (float)(rr0 - cum) + 0.5f;
      v0 = ((float)i + frac / (float)c) * 0.5f;
      f0 = true;
    }
    if (!f1 && c > 0 && cum + c > rr1) {
      float frac = (float)(rr1 - cum) + 0.5f;
      v1 = ((float)i + frac / (float)c) * 0.5f;
      f1 = true;
      break;
    }
    cum += c;
  }
  float med = 0.5f * (v0 + v1);
  float mean = (total > 0) ? (ssum[0] / (float)total) : 1.0f;
  float g = (med > 0.f) ? 1.0f / (med + 1e-6f) : 1.0f / (mean + 1e-6f);
  gptr[0] = g;
}

// MAIN: fused cdist^2 + exp + online accumulation. grid (16 s-chunks, 128 q-tiles)
// d2 = q2p[i] + s2[j] - 2 * (G @ S^T)(i,j)
__global__ void PrototypicalHead_6210522710389_kernel(
    const float* __restrict__ G, const float* __restrict__ S,
    const float* __restrict__ q2p, const float* __restrict__ s2,
    const float* __restrict__ svals, const float* __restrict__ gptr,
    float* __restrict__ part) {
  __shared__ alignas(16) float As[16][68];
  __shared__ alignas(16) float Bs[16][68];
  __shared__ float Sv[64];
  __shared__ float red[64][17];
  int t = threadIdx.x, tx = t & 15, ty = t >> 4;
  int sc = blockIdx.x, qt = blockIdx.y;
  int qbase = qt * 64;
  float gamma = gptr[0];
  float q2v[4];
#pragma unroll
  for (int r = 0; r < 4; ++r) q2v[r] = q2p[qbase + ty * 4 + r];
  float dAcc[4] = {0.f, 0.f, 0.f, 0.f}, nAcc[4] = {0.f, 0.f, 0.f, 0.f};

  for (int st = 0; st < 16; ++st) {
    int sbase = sc * 1024 + st * 64;
    __syncthreads();
    if (t < 64) Sv[t] = svals[sbase + t];
    float s2v[4];
#pragma unroll
    for (int c = 0; c < 4; ++c) s2v[c] = s2[sbase + tx * 4 + c];
    float acc[4][4] = {};
    for (int k0 = 0; k0 < 256; k0 += 16) {
      __syncthreads();
      int kk = t & 15, m0 = t >> 4;
#pragma unroll
      for (int p = 0; p < 4; ++p) {
        int m = m0 + p * 16;
        As[kk][m] = G[(size_t)(qbase + m) * kD + k0 + kk];
        Bs[kk][m] = S[(size_t)(sbase + m) * kD + k0 + kk];
      }
      __syncthreads();
#pragma unroll
      for (int k = 0; k < 16; ++k) {
        float4 a = *(const float4*)&As[k][ty * 4];
        float4 b = *(const float4*)&Bs[k][tx * 4];
        fma16(acc, a, b);
      }
    }
#pragma unroll
    for (int r = 0; r < 4; ++r)
#pragma unroll
      for (int c = 0; c < 4; ++c) {
        float d2 = fmaxf(q2v[r] + s2v[c] - 2.0f * acc[r][c], 0.0f);
        float e = __expf(-gamma * d2);
        dAcc[r] += e;
        nAcc[r] += e * Sv[tx * 4 + c];
      }
  }
  __syncthreads();
#pragma unroll
  for (int r = 0; r < 4; ++r) red[ty * 4 + r][tx] = dAcc[r];
  __syncthreads();
  if (t < 64) {
    float s = 0.f;
#pragma unroll
    for (int x = 0; x < 16; ++x) s += red[t][x];
    part[((size_t)(qbase + t) * 16 + sc) * 2 + 0] = s;
  }
  __syncthreads();
#pragma unroll
  for (int r = 0; r < 4; ++r) red[ty * 4 + r][tx] = nAcc[r];
  __syncthreads();
  if (t < 64) {
    float s = 0.f;
#pragma unroll
    for (int x = 0; x < 16; ++x) s += red[t][x];
    part[((size_t)(qbase + t) * 16 + sc) * 2 + 1] = s;
  }
}

__global__ void k_final_r12(const float* __restrict__ part, float* __restrict__ out1) {
  int q = blockIdx.x * 256 + threadIdx.x;
  const float* p = part + (size_t)q * 32;
  float d = 0.f, n = 0.f;
#pragma unroll
  for (int i = 0; i < 16; ++i) { d += p[2 * i]; n += p[2 * i + 1]; }
  out1[q] = n / d;
}

extern "C" void kernel_launch(void* const* d_in, const int* in_sizes, int n_in,
                              void* d_out, int out_size, void* d_ws, size_t ws_size,
                              hipStream_t stream) {
  (void)in_sizes; (void)n_in; (void)out_size; (void)ws_size;
  const float* SF = (const float*)d_in[0];   // fp32
  const int*   SL = (const int*)d_in[1];     // int32
  const float* SV = (const float*)d_in[2];   // fp32
  const float* QF = (const float*)d_in[3];   // fp32

  float* ws = (float*)d_ws;
  float* psum  = ws + OFF_PSUM;
  float* pcnt  = ws + OFF_PCNT;
  float* musum = ws + OFF_MUSUM;
  float* xtx   = ws + OFF_XTX;
  unsigned int* hist = (unsigned int*)(ws + OFF_HIST);
  float* ssum  = ws + OFF_SSUM;
  float* protos= ws + OFF_PROTO;
  float* mu    = ws + OFF_MU;
  float* cov   = ws + OFF_COV;
  float* rows  = ws + OFF_ROWS;
  float* cptr  = ws + OFF_C;
  float* gptr  = ws + OFF_C + 1;
  float* Y  = ws + OFF_Y;  float* Z  = ws + OFF_Z;  float* T = ws + OFF_T;
  float* Y2 = ws + OFF_Y2; float* Z2 = ws + OFF_Z2;
  float* M  = ws + OFF_M;
  float* s2 = ws + OFF_S2; float* q2p = ws + OFF_Q2P;
  float* part = ws + OFF_PART;
  float* G = ws + OFF_G;

  float* out0 = (float*)d_out;                   // f32 log_probs [8192 x 64]
  float* out1 = out0 + (size_t)kNQ * kC;         // f32 predictions [8192]

  k_zero_r12<<<(int)((ZERO_FLOATS + 255) / 256), 256, 0, stream>>>(ws);

  // classification
  k_proto_accum_r12<<<kNS / 4, 256, 0, stream>>>(SF, SL, psum, pcnt);
  k_proto_fin_r12<<<kC, 64, 0, stream>>>(psum, pcnt, protos);
  k_logits_r12<<<kNQ, 256, 0, stream>>>(QF, protos, out0);

  // regression: mean, cov
  k_colsum_r12<<<kNS / 256, 256, 0, stream>>>(SF, musum);
  k_mufin_r12<<<1, 256, 0, stream>>>(musum, mu);
  k_xtx_r12<<<dim3(16, 16), 256, 0, stream>>>(SF, xtx);
  k_cov_r12<<<256, 256, 0, stream>>>(xtx, mu, cov);

  // Newton-Schulz inverse sqrt of cov/c (10 coupled iterations)
  k_rowabs_r12<<<256, 64, 0, stream>>>(cov, rows);
  k_cnorm_r12<<<1, 64, 0, stream>>>(rows, cptr);
  k_nsinit_r12<<<256, 256, 0, stream>>>(cov, cptr, Y, Z);
  float *Yc = Y, *Zc = Z, *Yn = Y2, *Zn = Z2;
  for (int it = 0; it < 10; ++it) {
    k_ns_t_r12<<<16, 256, 0, stream>>>(Zc, Yc, T);
    k_ns_yz_r12<<<dim3(16, 2), 256, 0, stream>>>(Yc, Zc, T, Yn, Zn);
    float* tmp = Yc; Yc = Yn; Yn = tmp;
    tmp = Zc; Zc = Zn; Zn = tmp;
  }
  // Zc = (cov/c)^(-1/2);  M = Zc Zc / c = cov^-1
  k_msq_r12<<<16, 256, 0, stream>>>(Zc, cptr, M);

  // G = (Q - mu) @ M, then scalar row terms
  k_G_r12<<<dim3(4, kNQ / 64), 256, 0, stream>>>(QF, mu, M, G);
  k_q2p_r12<<<kNQ / 4, 256, 0, stream>>>(G, QF, mu, q2p);
  k_s2_r12<<<kNS / 64, 256, 0, stream>>>(SF, mu, M, s2);

  // sampled median -> gamma
  k_median_r12<<<256, 256, 0, stream>>>(G, SF, q2p, s2, hist, ssum);
  k_gamma_r12<<<1, 64, 0, stream>>>(hist, ssum, gptr);

  // fused cdist^2 + softmax numer/denom, then finalize
  PrototypicalHead_6210522710389_kernel<<<dim3(16, 128), 256, 0, stream>>>(
      G, SF, q2p, s2, SV, gptr, part);
  k_final_r12<<<kNQ / 256, 256, 0, stream>>>(part, out1);
}

// Round 13
// 1995.698 us; speedup vs baseline: 1.6303x; 1.6303x over previous
//
#include <hip/hip_runtime.h>
#include <hip/hip_bf16.h>

// Problem dims (fixed by setup_inputs)
constexpr int kNS = 16384;   // support rows
constexpr int kNQ = 8192;    // query rows
constexpr int kD  = 256;     // feature dim
constexpr int kC  = 64;      // classes

// R12 PASSED (3253 us). R13: k_median rewritten as GEMM-tiled histogram
// (was 1188 us latency-bound: 12% occupancy, 5.6% VALUBusy, serial
// shuffle-reduce dots); NS 10->8 iters (converged by 7); colsum wider grid.

// ---------------- workspace layout (float offsets into d_ws), ~11.8 MB ----
constexpr size_t OFF_PSUM  = 0;
constexpr size_t OFF_PCNT  = 16384;
constexpr size_t OFF_MUSUM = 16448;
constexpr size_t OFF_XTX   = 16704;
constexpr size_t OFF_HIST  = 82240;
constexpr size_t OFF_SSUM  = 84288;
constexpr size_t ZERO_FLOATS = 84352;
constexpr size_t OFF_PROTO = 84352;
constexpr size_t OFF_MU    = 100736;
constexpr size_t OFF_COV   = 100992;
constexpr size_t OFF_ROWS  = 166528;
constexpr size_t OFF_C     = 166784;
constexpr size_t OFF_Y     = 166800;
constexpr size_t OFF_Z     = 232336;
constexpr size_t OFF_T     = 297872;
constexpr size_t OFF_Y2    = 363408;
constexpr size_t OFF_Z2    = 428944;
constexpr size_t OFF_M     = 494480;
constexpr size_t OFF_S2    = 560016;
constexpr size_t OFF_Q2P   = 576400;
constexpr size_t OFF_PART  = 584592;
constexpr size_t OFF_G     = 846736;

__device__ __forceinline__ float waveReduceSum(float v) {
#pragma unroll
  for (int off = 32; off > 0; off >>= 1) v += __shfl_xor(v, off);
  return v;
}
__device__ __forceinline__ float waveReduceMax(float v) {
#pragma unroll
  for (int off = 32; off > 0; off >>= 1) v = fmaxf(v, __shfl_xor(v, off));
  return v;
}
__device__ __forceinline__ void fma16(float acc[4][4], float4 a, float4 b) {
  acc[0][0] += a.x*b.x; acc[0][1] += a.x*b.y; acc[0][2] += a.x*b.z; acc[0][3] += a.x*b.w;
  acc[1][0] += a.y*b.x; acc[1][1] += a.y*b.y; acc[1][2] += a.y*b.z; acc[1][3] += a.y*b.w;
  acc[2][0] += a.z*b.x; acc[2][1] += a.z*b.y; acc[2][2] += a.z*b.z; acc[2][3] += a.z*b.w;
  acc[3][0] += a.w*b.x; acc[3][1] += a.w*b.y; acc[3][2] += a.w*b.z; acc[3][3] += a.w*b.w;
}

__global__ void k_zero_r13(float* __restrict__ ws) {
  size_t i = (size_t)blockIdx.x * 256 + threadIdx.x;
  if (i < ZERO_FLOATS) ws[i] = 0.f;
}

// ---------------- classification path ----------------
__global__ void k_proto_accum_r13(const float* __restrict__ X, const int* __restrict__ lab,
                                  float* __restrict__ psum, float* __restrict__ pcnt) {
  int w = threadIdx.x >> 6, lane = threadIdx.x & 63;
  int row = blockIdx.x * 4 + w;
  float4 v = *(const float4*)&X[(size_t)row * kD + lane * 4];
  float ss = waveReduceSum(v.x*v.x + v.y*v.y + v.z*v.z + v.w*v.w);
  float inv = 1.0f / fmaxf(sqrtf(ss), 1e-8f);
  int l = lab[row];
  float* p = psum + (size_t)l * kD + lane * 4;
  atomicAdd(p + 0, v.x * inv); atomicAdd(p + 1, v.y * inv);
  atomicAdd(p + 2, v.z * inv); atomicAdd(p + 3, v.w * inv);
  if (lane == 0) atomicAdd(&pcnt[l], 1.0f);
}

__global__ void k_proto_fin_r13(const float* __restrict__ psum, const float* __restrict__ pcnt,
                                float* __restrict__ protos) {
  int c = blockIdx.x, lane = threadIdx.x;
  float4 v = *(const float4*)&psum[(size_t)c * kD + lane * 4];
  float cnt = fmaxf(pcnt[c], 1.0f);
  v.x /= cnt; v.y /= cnt; v.z /= cnt; v.w /= cnt;
  float ss = waveReduceSum(v.x*v.x + v.y*v.y + v.z*v.z + v.w*v.w);
  float inv = 1.0f / fmaxf(sqrtf(ss), 1e-8f);
  float4 o = {v.x*inv, v.y*inv, v.z*inv, v.w*inv};
  *(float4*)&protos[(size_t)c * kD + lane * 4] = o;
}

// one block (4 waves) per query: 64 dots + log_softmax, f32 out
__global__ void k_logits_r13(const float* __restrict__ Q, const float* __restrict__ protos,
                             float* __restrict__ out0) {
  __shared__ alignas(16) float qs[kD];
  __shared__ float lg[kC];
  __shared__ float wred[4];
  __shared__ float qis;
  int t = threadIdx.x, w = t >> 6, lane = t & 63;
  int qi = blockIdx.x;
  float myv = Q[(size_t)qi * kD + t];
  qs[t] = myv;
  float ss = waveReduceSum(myv * myv);
  if (lane == 0) wred[w] = ss;
  __syncthreads();
  if (t == 0) qis = 1.0f / fmaxf(sqrtf(wred[0] + wred[1] + wred[2] + wred[3]), 1e-8f);
  __syncthreads();
  float4 qv = *(const float4*)&qs[lane * 4];
  for (int cc = w * 16; cc < w * 16 + 16; ++cc) {
    float4 pv = *(const float4*)&protos[(size_t)cc * kD + lane * 4];
    float d = waveReduceSum(qv.x*pv.x + qv.y*pv.y + qv.z*pv.z + qv.w*pv.w);
    if (lane == 0) lg[cc] = d * qis;
  }
  __syncthreads();
  if (t < 64) {
    float v = lg[t];
    float m = waveReduceMax(v);
    float e = expf(v - m);
    float s = waveReduceSum(e);
    float lse = m + logf(s);
    out0[(size_t)qi * kC + t] = v - lse;
  }
}

// ---------------- regression path ----------------
__global__ void k_colsum_r13(const float* __restrict__ X, float* __restrict__ musum) {
  int t = threadIdx.x;
  int r0 = blockIdx.x * 64;
  float s = 0.f;
  for (int r = 0; r < 64; ++r) s += X[(size_t)(r0 + r) * kD + t];
  atomicAdd(&musum[t], s);
}
__global__ void k_mufin_r13(const float* __restrict__ musum, float* __restrict__ mu) {
  int t = threadIdx.x;
  mu[t] = musum[t] * (1.0f / (float)kNS);
}

__global__ void k_xtx_r13(const float* __restrict__ X, float* __restrict__ xtx) {
  __shared__ alignas(16) float As[16][68];
  __shared__ alignas(16) float Bs[16][68];
  int t = threadIdx.x, tx = t & 15, ty = t >> 4;
  int ab = (blockIdx.x >> 2) * 64, bb = (blockIdx.x & 3) * 64;
  int k0b = blockIdx.y * 1024;
  float acc[4][4] = {};
  for (int k0 = 0; k0 < 1024; k0 += 16) {
    __syncthreads();
    int j = t & 63, kr0 = t >> 6;
#pragma unroll
    for (int p = 0; p < 4; ++p) {
      int kr = kr0 + p * 4;
      size_t base = (size_t)(k0b + k0 + kr) * kD;
      As[kr][j] = X[base + ab + j];
      Bs[kr][j] = X[base + bb + j];
    }
    __syncthreads();
#pragma unroll
    for (int k = 0; k < 16; ++k) {
      float4 a = *(const float4*)&As[k][ty * 4];
      float4 b = *(const float4*)&Bs[k][tx * 4];
      fma16(acc, a, b);
    }
  }
#pragma unroll
  for (int r = 0; r < 4; ++r)
#pragma unroll
    for (int c = 0; c < 4; ++c)
      atomicAdd(&xtx[(size_t)(ab + ty * 4 + r) * kD + bb + tx * 4 + c], acc[r][c]);
}

__global__ void k_cov_r13(const float* __restrict__ xtx, const float* __restrict__ mu,
                          float* __restrict__ cov) {
  int i = blockIdx.x, j = threadIdx.x;
  float v = (xtx[(size_t)i * kD + j] - (float)kNS * mu[i] * mu[j]) * (1.0f / (float)(kNS - 1));
  if (i == j) v += 1e-4f;
  cov[(size_t)i * kD + j] = v;
}

__global__ void k_rowabs_r13(const float* __restrict__ cov, float* __restrict__ rows) {
  int row = blockIdx.x, lane = threadIdx.x;
  float4 v = *(const float4*)&cov[(size_t)row * kD + lane * 4];
  float s = waveReduceSum(fabsf(v.x) + fabsf(v.y) + fabsf(v.z) + fabsf(v.w));
  if (lane == 0) rows[row] = s;
}
__global__ void k_cnorm_r13(const float* __restrict__ rows, float* __restrict__ cptr) {
  int lane = threadIdx.x;
  float m = fmaxf(fmaxf(rows[lane], rows[lane + 64]),
                  fmaxf(rows[lane + 128], rows[lane + 192]));
  m = waveReduceMax(m);
  if (lane == 0) cptr[0] = m;
}
__global__ void k_nsinit_r13(const float* __restrict__ cov, const float* __restrict__ cptr,
                             float* __restrict__ Y, float* __restrict__ Z) {
  int i = blockIdx.x, j = threadIdx.x;
  float invc = 1.0f / cptr[0];
  size_t idx = (size_t)i * kD + j;
  Y[idx] = cov[idx] * invc;
  Z[idx] = (i == j) ? 1.0f : 0.0f;
}

// T = 1.5 I - 0.5 * (Z @ Y)
__global__ void k_ns_t_r13(const float* __restrict__ Zc, const float* __restrict__ Yc,
                           float* __restrict__ T) {
  __shared__ alignas(16) float As[16][68];
  __shared__ alignas(16) float Bs[16][68];
  int t = threadIdx.x, tx = t & 15, ty = t >> 4;
  int mb = (blockIdx.x >> 2) * 64, nb = (blockIdx.x & 3) * 64;
  float acc[4][4] = {};
  for (int k0 = 0; k0 < 256; k0 += 16) {
    __syncthreads();
    {
      int kk = t & 15, m0 = t >> 4;
#pragma unroll
      for (int p = 0; p < 4; ++p) {
        int m = m0 + p * 16;
        As[kk][m] = Zc[(size_t)(mb + m) * kD + k0 + kk];
      }
      int j = t & 63, kr0 = t >> 6;
#pragma unroll
      for (int p = 0; p < 4; ++p) {
        int kr = kr0 + p * 4;
        Bs[kr][j] = Yc[(size_t)(k0 + kr) * kD + nb + j];
      }
    }
    __syncthreads();
#pragma unroll
    for (int k = 0; k < 16; ++k) {
      float4 a = *(const float4*)&As[k][ty * 4];
      float4 b = *(const float4*)&Bs[k][tx * 4];
      fma16(acc, a, b);
    }
  }
#pragma unroll
  for (int r = 0; r < 4; ++r)
#pragma unroll
    for (int c = 0; c < 4; ++c) {
      int gi = mb + ty * 4 + r, gj = nb + tx * 4 + c;
      T[(size_t)gi * kD + gj] = (gi == gj ? 1.5f : 0.0f) - 0.5f * acc[r][c];
    }
}

// blockIdx.y==0: Yn = Yc @ T ; blockIdx.y==1: Zn = T @ Zc
__global__ void k_ns_yz_r13(const float* __restrict__ Yc, const float* __restrict__ Zc,
                            const float* __restrict__ T, float* __restrict__ Yn,
                            float* __restrict__ Zn) {
  const float* A; const float* B; float* O;
  if (blockIdx.y == 0) { A = Yc; B = T; O = Yn; } else { A = T; B = Zc; O = Zn; }
  __shared__ alignas(16) float As[16][68];
  __shared__ alignas(16) float Bs[16][68];
  int t = threadIdx.x, tx = t & 15, ty = t >> 4;
  int mb = (blockIdx.x >> 2) * 64, nb = (blockIdx.x & 3) * 64;
  float acc[4][4] = {};
  for (int k0 = 0; k0 < 256; k0 += 16) {
    __syncthreads();
    {
      int kk = t & 15, m0 = t >> 4;
#pragma unroll
      for (int p = 0; p < 4; ++p) {
        int m = m0 + p * 16;
        As[kk][m] = A[(size_t)(mb + m) * kD + k0 + kk];
      }
      int j = t & 63, kr0 = t >> 6;
#pragma unroll
      for (int p = 0; p < 4; ++p) {
        int kr = kr0 + p * 4;
        Bs[kr][j] = B[(size_t)(k0 + kr) * kD + nb + j];
      }
    }
    __syncthreads();
#pragma unroll
    for (int k = 0; k < 16; ++k) {
      float4 a = *(const float4*)&As[k][ty * 4];
      float4 b = *(const float4*)&Bs[k][tx * 4];
      fma16(acc, a, b);
    }
  }
#pragma unroll
  for (int r = 0; r < 4; ++r) {
    int gi = mb + ty * 4 + r;
    float4 o = {acc[r][0], acc[r][1], acc[r][2], acc[r][3]};
    *(float4*)&O[(size_t)gi * kD + nb + tx * 4] = o;
  }
}

// M = Zf @ Zf / c   (cov^-1, since Zf = (cov/c)^(-1/2))
__global__ void k_msq_r13(const float* __restrict__ Zf, const float* __restrict__ cptr,
                          float* __restrict__ M) {
  __shared__ alignas(16) float As[16][68];
  __shared__ alignas(16) float Bs[16][68];
  int t = threadIdx.x, tx = t & 15, ty = t >> 4;
  int mb = (blockIdx.x >> 2) * 64, nb = (blockIdx.x & 3) * 64;
  float acc[4][4] = {};
  for (int k0 = 0; k0 < 256; k0 += 16) {
    __syncthreads();
    {
      int kk = t & 15, m0 = t >> 4;
#pragma unroll
      for (int p = 0; p < 4; ++p) {
        int m = m0 + p * 16;
        As[kk][m] = Zf[(size_t)(mb + m) * kD + k0 + kk];
      }
      int j = t & 63, kr0 = t >> 6;
#pragma unroll
      for (int p = 0; p < 4; ++p) {
        int kr = kr0 + p * 4;
        Bs[kr][j] = Zf[(size_t)(k0 + kr) * kD + nb + j];
      }
    }
    __syncthreads();
#pragma unroll
    for (int k = 0; k < 16; ++k) {
      float4 a = *(const float4*)&As[k][ty * 4];
      float4 b = *(const float4*)&Bs[k][tx * 4];
      fma16(acc, a, b);
    }
  }
  float invc = 1.0f / cptr[0];
#pragma unroll
  for (int r = 0; r < 4; ++r) {
    int gi = mb + ty * 4 + r;
    float4 o = {acc[r][0] * invc, acc[r][1] * invc, acc[r][2] * invc, acc[r][3] * invc};
    *(float4*)&M[(size_t)gi * kD + nb + tx * 4] = o;
  }
}

// G = (Q - mu) @ M   [kNQ x kD]
__global__ void k_G_r13(const float* __restrict__ Q, const float* __restrict__ mu,
                        const float* __restrict__ M, float* __restrict__ G) {
  __shared__ alignas(16) float As[16][68];
  __shared__ alignas(16) float Bs[16][68];
  int t = threadIdx.x, tx = t & 15, ty = t >> 4;
  int nb = blockIdx.x * 64;
  int mb = blockIdx.y * 64;
  float acc[4][4] = {};
  for (int k0 = 0; k0 < 256; k0 += 16) {
    __syncthreads();
    {
      int kk = t & 15, m0 = t >> 4;
      float muk = mu[k0 + kk];
#pragma unroll
      for (int p = 0; p < 4; ++p) {
        int m = m0 + p * 16;
        As[kk][m] = Q[(size_t)(mb + m) * kD + k0 + kk] - muk;
      }
      int j = t & 63, kr0 = t >> 6;
#pragma unroll
      for (int p = 0; p < 4; ++p) {
        int kr = kr0 + p * 4;
        Bs[kr][j] = M[(size_t)(k0 + kr) * kD + nb + j];
      }
    }
    __syncthreads();
#pragma unroll
    for (int k = 0; k < 16; ++k) {
      float4 a = *(const float4*)&As[k][ty * 4];
      float4 b = *(const float4*)&Bs[k][tx * 4];
      fma16(acc, a, b);
    }
  }
#pragma unroll
  for (int r = 0; r < 4; ++r) {
    int gi = mb + ty * 4 + r;
    float4 o = {acc[r][0], acc[r][1], acc[r][2], acc[r][3]};
    *(float4*)&G[(size_t)gi * kD + nb + tx * 4] = o;
  }
}

// q2p[i] = G_i . (Q_i + mu)
__global__ void k_q2p_r13(const float* __restrict__ G, const float* __restrict__ Q,
                          const float* __restrict__ mu, float* __restrict__ q2p) {
  int w = threadIdx.x >> 6, lane = threadIdx.x & 63;
  int row = blockIdx.x * 4 + w;
  float4 g = *(const float4*)&G[(size_t)row * kD + lane * 4];
  float4 q = *(const float4*)&Q[(size_t)row * kD + lane * 4];
  float4 m = *(const float4*)&mu[lane * 4];
  float ss = waveReduceSum(g.x*(q.x+m.x) + g.y*(q.y+m.y) + g.z*(q.z+m.z) + g.w*(q.w+m.w));
  if (lane == 0) q2p[row] = ss;
}

// s2[j] = (S_j - mu) M (S_j - mu), per 64-row chunk
__global__ void k_s2_r13(const float* __restrict__ S, const float* __restrict__ mu,
                         const float* __restrict__ M, float* __restrict__ s2) {
  __shared__ alignas(16) float As[16][68];
  __shared__ alignas(16) float Bs[16][68];
  __shared__ float red[64][17];
  int t = threadIdx.x, tx = t & 15, ty = t >> 4;
  int mb = blockIdx.x * 64;
  float partial[4] = {0.f, 0.f, 0.f, 0.f};
  for (int ntile = 0; ntile < 4; ++ntile) {
    int nb = ntile * 64;
    float acc[4][4] = {};
    for (int k0 = 0; k0 < 256; k0 += 16) {
      __syncthreads();
      {
        int kk = t & 15, m0 = t >> 4;
        float muk = mu[k0 + kk];
#pragma unroll
        for (int p = 0; p < 4; ++p) {
          int m = m0 + p * 16;
          As[kk][m] = S[(size_t)(mb + m) * kD + k0 + kk] - muk;
        }
        int j = t & 63, kr0 = t >> 6;
#pragma unroll
        for (int p = 0; p < 4; ++p) {
          int kr = kr0 + p * 4;
          Bs[kr][j] = M[(size_t)(k0 + kr) * kD + nb + j];
        }
      }
      __syncthreads();
#pragma unroll
      for (int k = 0; k < 16; ++k) {
        float4 a = *(const float4*)&As[k][ty * 4];
        float4 b = *(const float4*)&Bs[k][tx * 4];
        fma16(acc, a, b);
      }
    }
#pragma unroll
    for (int r = 0; r < 4; ++r) {
      int gi = mb + ty * 4 + r;
#pragma unroll
      for (int c = 0; c < 4; ++c) {
        int gj = nb + tx * 4 + c;
        partial[r] += acc[r][c] * (S[(size_t)gi * kD + gj] - mu[gj]);
      }
    }
  }
  __syncthreads();
#pragma unroll
  for (int r = 0; r < 4; ++r) red[ty * 4 + r][tx] = partial[r];
  __syncthreads();
  if (t < 64) {
    float s = 0.f;
#pragma unroll
    for (int x = 0; x < 16; ++x) s += red[t][x];
    s2[mb + t] = s;
  }
}

// GEMM-tiled sampled-median histogram. Samples: q = 8*i (1024), s = 8*j (2048).
// Grid (32 s-tiles, 16 q-tiles); each block: 64x64 d2 tile + LDS histogram.
__global__ void k_median_r13(const float* __restrict__ G, const float* __restrict__ S,
                             const float* __restrict__ q2p, const float* __restrict__ s2,
                             unsigned int* __restrict__ hist, float* __restrict__ ssum) {
  __shared__ alignas(16) float As[16][68];
  __shared__ alignas(16) float Bs[16][68];
  __shared__ unsigned int h[2048];
  __shared__ float fred[4];
  int t = threadIdx.x, tx = t & 15, ty = t >> 4;
  int stile = blockIdx.x, qtile = blockIdx.y;
  for (int i = t; i < 2048; i += 256) h[i] = 0u;

  float acc[4][4] = {};
  for (int k0 = 0; k0 < 256; k0 += 16) {
    __syncthreads();
    {
      int kk = t & 15, m0 = t >> 4;
#pragma unroll
      for (int p = 0; p < 4; ++p) {
        int m = m0 + p * 16;
        As[kk][m] = G[(size_t)((qtile * 64 + m) * 8) * kD + k0 + kk];
        Bs[kk][m] = S[(size_t)((stile * 64 + m) * 8) * kD + k0 + kk];
      }
    }
    __syncthreads();
#pragma unroll
    for (int k = 0; k < 16; ++k) {
      float4 a = *(const float4*)&As[k][ty * 4];
      float4 b = *(const float4*)&Bs[k][tx * 4];
      fma16(acc, a, b);
    }
  }
  float fsum = 0.f;
#pragma unroll
  for (int r = 0; r < 4; ++r) {
    int qi = (qtile * 64 + ty * 4 + r) * 8;
    float q2v = q2p[qi];
#pragma unroll
    for (int c = 0; c < 4; ++c) {
      int sj = (stile * 64 + tx * 4 + c) * 8;
      float d2 = fmaxf(q2v + s2[sj] - 2.0f * acc[r][c], 0.0f);
      fsum += d2;
      int bin = (int)(d2 * 2.0f);
      bin = bin > 2047 ? 2047 : bin;
      atomicAdd(&h[bin], 1u);
    }
  }
  // reduce fsum: wave -> block -> global
  float wsum = waveReduceSum(fsum);
  if ((t & 63) == 0) fred[t >> 6] = wsum;
  __syncthreads();
  if (t == 0) atomicAdd(ssum, fred[0] + fred[1] + fred[2] + fred[3]);
  for (int i = t; i < 2048; i += 256)
    if (h[i]) atomicAdd(&hist[i], h[i]);
}

__global__ void k_gamma_r13(const unsigned int* __restrict__ hist,
                            const float* __restrict__ ssum, float* __restrict__ gptr) {
  if (threadIdx.x != 0) return;
  unsigned long long total = 0;
  for (int i = 0; i < 2048; ++i) total += (unsigned long long)hist[i];
  unsigned long long rr0 = (total - 1) / 2, rr1 = total / 2;
  float v0 = 0.f, v1 = 0.f;
  bool f0 = false, f1 = false;
  unsigned long long cum = 0;
  for (int i = 0; i < 2048; ++i) {
    unsigned int c = hist[i];
    if (!f0 && c > 0 && cum + c > rr0) {
      float frac = (float)(rr0 - cum) + 0.5f;
      v0 = ((float)i + frac / (float)c) * 0.5f;
      f0 = true;
    }
    if (!f1 && c > 0 && cum + c > rr1) {
      float frac = (float)(rr1 - cum) + 0.5f;
      v1 = ((float)i + frac / (float)c) * 0.5f;
      f1 = true;
      break;
    }
    cum += c;
  }
  float med = 0.5f * (v0 + v1);
  float mean = (total > 0) ? (ssum[0] / (float)total) : 1.0f;
  float g = (med > 0.f) ? 1.0f / (med + 1e-6f) : 1.0f / (mean + 1e-6f);
  gptr[0] = g;
}

// MAIN: fused cdist^2 + exp + online accumulation. grid (16 s-chunks, 128 q-tiles)
// d2 = q2p[i] + s2[j] - 2 * (G @ S^T)(i,j)
__global__ void PrototypicalHead_6210522710389_kernel(
    const float* __restrict__ G, const float* __restrict__ S,
    const float* __restrict__ q2p, const float* __restrict__ s2,
    const float* __restrict__ svals, const float* __restrict__ gptr,
    float* __restrict__ part) {
  __shared__ alignas(16) float As[16][68];
  __shared__ alignas(16) float Bs[16][68];
  __shared__ float Sv[64];
  __shared__ float red[64][17];
  int t = threadIdx.x, tx = t & 15, ty = t >> 4;
  int sc = blockIdx.x, qt = blockIdx.y;
  int qbase = qt * 64;
  float gamma = gptr[0];
  float q2v[4];
#pragma unroll
  for (int r = 0; r < 4; ++r) q2v[r] = q2p[qbase + ty * 4 + r];
  float dAcc[4] = {0.f, 0.f, 0.f, 0.f}, nAcc[4] = {0.f, 0.f, 0.f, 0.f};

  for (int st = 0; st < 16; ++st) {
    int sbase = sc * 1024 + st * 64;
    __syncthreads();
    if (t < 64) Sv[t] = svals[sbase + t];
    float s2v[4];
#pragma unroll
    for (int c = 0; c < 4; ++c) s2v[c] = s2[sbase + tx * 4 + c];
    float acc[4][4] = {};
    for (int k0 = 0; k0 < 256; k0 += 16) {
      __syncthreads();
      int kk = t & 15, m0 = t >> 4;
#pragma unroll
      for (int p = 0; p < 4; ++p) {
        int m = m0 + p * 16;
        As[kk][m] = G[(size_t)(qbase + m) * kD + k0 + kk];
        Bs[kk][m] = S[(size_t)(sbase + m) * kD + k0 + kk];
      }
      __syncthreads();
#pragma unroll
      for (int k = 0; k < 16; ++k) {
        float4 a = *(const float4*)&As[k][ty * 4];
        float4 b = *(const float4*)&Bs[k][tx * 4];
        fma16(acc, a, b);
      }
    }
#pragma unroll
    for (int r = 0; r < 4; ++r)
#pragma unroll
      for (int c = 0; c < 4; ++c) {
        float d2 = fmaxf(q2v[r] + s2v[c] - 2.0f * acc[r][c], 0.0f);
        float e = __expf(-gamma * d2);
        dAcc[r] += e;
        nAcc[r] += e * Sv[tx * 4 + c];
      }
  }
  __syncthreads();
#pragma unroll
  for (int r = 0; r < 4; ++r) red[ty * 4 + r][tx] = dAcc[r];
  __syncthreads();
  if (t < 64) {
    float s = 0.f;
#pragma unroll
    for (int x = 0; x < 16; ++x) s += red[t][x];
    part[((size_t)(qbase + t) * 16 + sc) * 2 + 0] = s;
  }
  __syncthreads();
#pragma unroll
  for (int r = 0; r < 4; ++r) red[ty * 4 + r][tx] = nAcc[r];
  __syncthreads();
  if (t < 64) {
    float s = 0.f;
#pragma unroll
    for (int x = 0; x < 16; ++x) s += red[t][x];
    part[((size_t)(qbase + t) * 16 + sc) * 2 + 1] = s;
  }
}

__global__ void k_final_r13(const float* __restrict__ part, float* __restrict__ out1) {
  int q = blockIdx.x * 256 + threadIdx.x;
  const float* p = part + (size_t)q * 32;
  float d = 0.f, n = 0.f;
#pragma unroll
  for (int i = 0; i < 16; ++i) { d += p[2 * i]; n += p[2 * i + 1]; }
  out1[q] = n / d;
}

extern "C" void kernel_launch(void* const* d_in, const int* in_sizes, int n_in,
                              void* d_out, int out_size, void* d_ws, size_t ws_size,
                              hipStream_t stream) {
  (void)in_sizes; (void)n_in; (void)out_size; (void)ws_size;
  const float* SF = (const float*)d_in[0];   // fp32
  const int*   SL = (const int*)d_in[1];     // int32
  const float* SV = (const float*)d_in[2];   // fp32
  const float* QF = (const float*)d_in[3];   // fp32

  float* ws = (float*)d_ws;
  float* psum  = ws + OFF_PSUM;
  float* pcnt  = ws + OFF_PCNT;
  float* musum = ws + OFF_MUSUM;
  float* xtx   = ws + OFF_XTX;
  unsigned int* hist = (unsigned int*)(ws + OFF_HIST);
  float* ssum  = ws + OFF_SSUM;
  float* protos= ws + OFF_PROTO;
  float* mu    = ws + OFF_MU;
  float* cov   = ws + OFF_COV;
  float* rows  = ws + OFF_ROWS;
  float* cptr  = ws + OFF_C;
  float* gptr  = ws + OFF_C + 1;
  float* Y  = ws + OFF_Y;  float* Z  = ws + OFF_Z;  float* T = ws + OFF_T;
  float* Y2 = ws + OFF_Y2; float* Z2 = ws + OFF_Z2;
  float* M  = ws + OFF_M;
  float* s2 = ws + OFF_S2; float* q2p = ws + OFF_Q2P;
  float* part = ws + OFF_PART;
  float* G = ws + OFF_G;

  float* out0 = (float*)d_out;                   // f32 log_probs [8192 x 64]
  float* out1 = out0 + (size_t)kNQ * kC;         // f32 predictions [8192]

  k_zero_r13<<<(int)((ZERO_FLOATS + 255) / 256), 256, 0, stream>>>(ws);

  // classification
  k_proto_accum_r13<<<kNS / 4, 256, 0, stream>>>(SF, SL, psum, pcnt);
  k_proto_fin_r13<<<kC, 64, 0, stream>>>(psum, pcnt, protos);
  k_logits_r13<<<kNQ, 256, 0, stream>>>(QF, protos, out0);

  // regression: mean, cov
  k_colsum_r13<<<kNS / 64, 256, 0, stream>>>(SF, musum);
  k_mufin_r13<<<1, 256, 0, stream>>>(musum, mu);
  k_xtx_r13<<<dim3(16, 16), 256, 0, stream>>>(SF, xtx);
  k_cov_r13<<<256, 256, 0, stream>>>(xtx, mu, cov);

  // Newton-Schulz inverse sqrt of cov/c (8 coupled iterations; converged by 7)
  k_rowabs_r13<<<256, 64, 0, stream>>>(cov, rows);
  k_cnorm_r13<<<1, 64, 0, stream>>>(rows, cptr);
  k_nsinit_r13<<<256, 256, 0, stream>>>(cov, cptr, Y, Z);
  float *Yc = Y, *Zc = Z, *Yn = Y2, *Zn = Z2;
  for (int it = 0; it < 8; ++it) {
    k_ns_t_r13<<<16, 256, 0, stream>>>(Zc, Yc, T);
    k_ns_yz_r13<<<dim3(16, 2), 256, 0, stream>>>(Yc, Zc, T, Yn, Zn);
    float* tmp = Yc; Yc = Yn; Yn = tmp;
    tmp = Zc; Zc = Zn; Zn = tmp;
  }
  // Zc = (cov/c)^(-1/2);  M = Zc Zc / c = cov^-1
  k_msq_r13<<<16, 256, 0, stream>>>(Zc, cptr, M);

  // G = (Q - mu) @ M, then scalar row terms
  k_G_r13<<<dim3(4, kNQ / 64), 256, 0, stream>>>(QF, mu, M, G);
  k_q2p_r13<<<kNQ / 4, 256, 0, stream>>>(G, QF, mu, q2p);
  k_s2_r13<<<kNS / 64, 256, 0, stream>>>(SF, mu, M, s2);

  // sampled median (GEMM-tiled histogram) -> gamma
  k_median_r13<<<dim3(32, 16), 256, 0, stream>>>(G, SF, q2p, s2, hist, ssum);
  k_gamma_r13<<<1, 64, 0, stream>>>(hist, ssum, gptr);

  // fused cdist^2 + softmax numer/denom, then finalize
  PrototypicalHead_6210522710389_kernel<<<dim3(16, 128), 256, 0, stream>>>(
      G, SF, q2p, s2, SV, gptr, part);
  k_final_r13<<<kNQ / 256, 256, 0, stream>>>(part, out1);
}

// Round 14
// 1401.782 us; speedup vs baseline: 2.3211x; 1.4237x over previous
//
#include <hip/hip_runtime.h>
#include <hip/hip_bf16.h>

// Problem dims (fixed by setup_inputs)
constexpr int kNS = 16384;   // support rows
constexpr int kNQ = 8192;    // query rows
constexpr int kD  = 256;     // feature dim
constexpr int kC  = 64;      // classes

// R13 PASSED (1996 us; main fused pass 1083 us, VALU-bound, MfmaUtil=0).
// R14: main pass -> bf16 MFMA (16x16x32), LDS-free/barrier-free: A-frags
// (G rows) preloaded once per wave, B (S rows) streamed from L2. d2 error
// from bf16 rounding ~0.12 abs on ~512 -> pred error ~1e-6 (margin 2.8x).

// ---------------- workspace layout (float offsets into d_ws), ~24.4 MB ----
constexpr size_t OFF_PSUM  = 0;
constexpr size_t OFF_PCNT  = 16384;
constexpr size_t OFF_MUSUM = 16448;
constexpr size_t OFF_XTX   = 16704;
constexpr size_t OFF_HIST  = 82240;
constexpr size_t OFF_SSUM  = 84288;
constexpr size_t ZERO_FLOATS = 84352;
constexpr size_t OFF_PROTO = 84352;
constexpr size_t OFF_MU    = 100736;
constexpr size_t OFF_COV   = 100992;
constexpr size_t OFF_ROWS  = 166528;
constexpr size_t OFF_C     = 166784;
constexpr size_t OFF_Y     = 166800;
constexpr size_t OFF_Z     = 232336;
constexpr size_t OFF_T     = 297872;
constexpr size_t OFF_Y2    = 363408;
constexpr size_t OFF_Z2    = 428944;
constexpr size_t OFF_M     = 494480;
constexpr size_t OFF_S2    = 560016;
constexpr size_t OFF_Q2P   = 576400;
constexpr size_t OFF_PART  = 584592;
constexpr size_t OFF_G     = 846736;     // 8192*256 f32
constexpr size_t OFF_SH    = 2943888;    // 16384*256 bf16 (2,097,152 floats)
constexpr size_t OFF_GH    = 5041040;    // 8192*256 bf16 (1,048,576 floats)

typedef __attribute__((ext_vector_type(8))) short bf16x8;   // 8 bf16 = 4 VGPRs
typedef __attribute__((ext_vector_type(4))) float f32x4;

// f32 -> bf16 (round to nearest even), stored as u16
__device__ __forceinline__ unsigned short f2bf(float f) {
  unsigned int w; __builtin_memcpy(&w, &f, 4);
  unsigned int r = (w + 0x7FFFu + ((w >> 16) & 1u)) >> 16;
  return (unsigned short)r;
}

__device__ __forceinline__ float waveReduceSum(float v) {
#pragma unroll
  for (int off = 32; off > 0; off >>= 1) v += __shfl_xor(v, off);
  return v;
}
__device__ __forceinline__ float waveReduceMax(float v) {
#pragma unroll
  for (int off = 32; off > 0; off >>= 1) v = fmaxf(v, __shfl_xor(v, off));
  return v;
}
__device__ __forceinline__ void fma16(float acc[4][4], float4 a, float4 b) {
  acc[0][0] += a.x*b.x; acc[0][1] += a.x*b.y; acc[0][2] += a.x*b.z; acc[0][3] += a.x*b.w;
  acc[1][0] += a.y*b.x; acc[1][1] += a.y*b.y; acc[1][2] += a.y*b.z; acc[1][3] += a.y*b.w;
  acc[2][0] += a.z*b.x; acc[2][1] += a.z*b.y; acc[2][2] += a.z*b.z; acc[2][3] += a.z*b.w;
  acc[3][0] += a.w*b.x; acc[3][1] += a.w*b.y; acc[3][2] += a.w*b.z; acc[3][3] += a.w*b.w;
}

__global__ void k_zero_r14(float* __restrict__ ws) {
  size_t i = (size_t)blockIdx.x * 256 + threadIdx.x;
  if (i < ZERO_FLOATS) ws[i] = 0.f;
}

// vectorized f32 -> bf16 conversion (n4 = n/4)
__global__ void k_tobf16_r14(const float* __restrict__ in,
                             unsigned short* __restrict__ out, int n4) {
  int i = blockIdx.x * 256 + threadIdx.x;
  if (i >= n4) return;
  float4 v = ((const float4*)in)[i];
  ushort4 o;
  o.x = f2bf(v.x); o.y = f2bf(v.y); o.z = f2bf(v.z); o.w = f2bf(v.w);
  ((ushort4*)out)[i] = o;
}

// ---------------- classification path ----------------
__global__ void k_proto_accum_r14(const float* __restrict__ X, const int* __restrict__ lab,
                                  float* __restrict__ psum, float* __restrict__ pcnt) {
  int w = threadIdx.x >> 6, lane = threadIdx.x & 63;
  int row = blockIdx.x * 4 + w;
  float4 v = *(const float4*)&X[(size_t)row * kD + lane * 4];
  float ss = waveReduceSum(v.x*v.x + v.y*v.y + v.z*v.z + v.w*v.w);
  float inv = 1.0f / fmaxf(sqrtf(ss), 1e-8f);
  int l = lab[row];
  float* p = psum + (size_t)l * kD + lane * 4;
  atomicAdd(p + 0, v.x * inv); atomicAdd(p + 1, v.y * inv);
  atomicAdd(p + 2, v.z * inv); atomicAdd(p + 3, v.w * inv);
  if (lane == 0) atomicAdd(&pcnt[l], 1.0f);
}

__global__ void k_proto_fin_r14(const float* __restrict__ psum, const float* __restrict__ pcnt,
                                float* __restrict__ protos) {
  int c = blockIdx.x, lane = threadIdx.x;
  float4 v = *(const float4*)&psum[(size_t)c * kD + lane * 4];
  float cnt = fmaxf(pcnt[c], 1.0f);
  v.x /= cnt; v.y /= cnt; v.z /= cnt; v.w /= cnt;
  float ss = waveReduceSum(v.x*v.x + v.y*v.y + v.z*v.z + v.w*v.w);
  float inv = 1.0f / fmaxf(sqrtf(ss), 1e-8f);
  float4 o = {v.x*inv, v.y*inv, v.z*inv, v.w*inv};
  *(float4*)&protos[(size_t)c * kD + lane * 4] = o;
}

__global__ void k_logits_r14(const float* __restrict__ Q, const float* __restrict__ protos,
                             float* __restrict__ out0) {
  __shared__ alignas(16) float qs[kD];
  __shared__ float lg[kC];
  __shared__ float wred[4];
  __shared__ float qis;
  int t = threadIdx.x, w = t >> 6, lane = t & 63;
  int qi = blockIdx.x;
  float myv = Q[(size_t)qi * kD + t];
  qs[t] = myv;
  float ss = waveReduceSum(myv * myv);
  if (lane == 0) wred[w] = ss;
  __syncthreads();
  if (t == 0) qis = 1.0f / fmaxf(sqrtf(wred[0] + wred[1] + wred[2] + wred[3]), 1e-8f);
  __syncthreads();
  float4 qv = *(const float4*)&qs[lane * 4];
  for (int cc = w * 16; cc < w * 16 + 16; ++cc) {
    float4 pv = *(const float4*)&protos[(size_t)cc * kD + lane * 4];
    float d = waveReduceSum(qv.x*pv.x + qv.y*pv.y + qv.z*pv.z + qv.w*pv.w);
    if (lane == 0) lg[cc] = d * qis;
  }
  __syncthreads();
  if (t < 64) {
    float v = lg[t];
    float m = waveReduceMax(v);
    float e = expf(v - m);
    float s = waveReduceSum(e);
    float lse = m + logf(s);
    out0[(size_t)qi * kC + t] = v - lse;
  }
}

// ---------------- regression path ----------------
__global__ void k_colsum_r14(const float* __restrict__ X, float* __restrict__ musum) {
  int t = threadIdx.x;
  int r0 = blockIdx.x * 64;
  float s = 0.f;
  for (int r = 0; r < 64; ++r) s += X[(size_t)(r0 + r) * kD + t];
  atomicAdd(&musum[t], s);
}
__global__ void k_mufin_r14(const float* __restrict__ musum, float* __restrict__ mu) {
  int t = threadIdx.x;
  mu[t] = musum[t] * (1.0f / (float)kNS);
}

__global__ void k_xtx_r14(const float* __restrict__ X, float* __restrict__ xtx) {
  __shared__ alignas(16) float As[16][68];
  __shared__ alignas(16) float Bs[16][68];
  int t = threadIdx.x, tx = t & 15, ty = t >> 4;
  int ab = (blockIdx.x >> 2) * 64, bb = (blockIdx.x & 3) * 64;
  int k0b = blockIdx.y * 1024;
  float acc[4][4] = {};
  for (int k0 = 0; k0 < 1024; k0 += 16) {
    __syncthreads();
    int j = t & 63, kr0 = t >> 6;
#pragma unroll
    for (int p = 0; p < 4; ++p) {
      int kr = kr0 + p * 4;
      size_t base = (size_t)(k0b + k0 + kr) * kD;
      As[kr][j] = X[base + ab + j];
      Bs[kr][j] = X[base + bb + j];
    }
    __syncthreads();
#pragma unroll
    for (int k = 0; k < 16; ++k) {
      float4 a = *(const float4*)&As[k][ty * 4];
      float4 b = *(const float4*)&Bs[k][tx * 4];
      fma16(acc, a, b);
    }
  }
#pragma unroll
  for (int r = 0; r < 4; ++r)
#pragma unroll
    for (int c = 0; c < 4; ++c)
      atomicAdd(&xtx[(size_t)(ab + ty * 4 + r) * kD + bb + tx * 4 + c], acc[r][c]);
}

__global__ void k_cov_r14(const float* __restrict__ xtx, const float* __restrict__ mu,
                          float* __restrict__ cov) {
  int i = blockIdx.x, j = threadIdx.x;
  float v = (xtx[(size_t)i * kD + j] - (float)kNS * mu[i] * mu[j]) * (1.0f / (float)(kNS - 1));
  if (i == j) v += 1e-4f;
  cov[(size_t)i * kD + j] = v;
}

__global__ void k_rowabs_r14(const float* __restrict__ cov, float* __restrict__ rows) {
  int row = blockIdx.x, lane = threadIdx.x;
  float4 v = *(const float4*)&cov[(size_t)row * kD + lane * 4];
  float s = waveReduceSum(fabsf(v.x) + fabsf(v.y) + fabsf(v.z) + fabsf(v.w));
  if (lane == 0) rows[row] = s;
}
__global__ void k_cnorm_r14(const float* __restrict__ rows, float* __restrict__ cptr) {
  int lane = threadIdx.x;
  float m = fmaxf(fmaxf(rows[lane], rows[lane + 64]),
                  fmaxf(rows[lane + 128], rows[lane + 192]));
  m = waveReduceMax(m);
  if (lane == 0) cptr[0] = m;
}
__global__ void k_nsinit_r14(const float* __restrict__ cov, const float* __restrict__ cptr,
                             float* __restrict__ Y, float* __restrict__ Z) {
  int i = blockIdx.x, j = threadIdx.x;
  float invc = 1.0f / cptr[0];
  size_t idx = (size_t)i * kD + j;
  Y[idx] = cov[idx] * invc;
  Z[idx] = (i == j) ? 1.0f : 0.0f;
}

// T = 1.5 I - 0.5 * (Z @ Y)
__global__ void k_ns_t_r14(const float* __restrict__ Zc, const float* __restrict__ Yc,
                           float* __restrict__ T) {
  __shared__ alignas(16) float As[16][68];
  __shared__ alignas(16) float Bs[16][68];
  int t = threadIdx.x, tx = t & 15, ty = t >> 4;
  int mb = (blockIdx.x >> 2) * 64, nb = (blockIdx.x & 3) * 64;
  float acc[4][4] = {};
  for (int k0 = 0; k0 < 256; k0 += 16) {
    __syncthreads();
    {
      int kk = t & 15, m0 = t >> 4;
#pragma unroll
      for (int p = 0; p < 4; ++p) {
        int m = m0 + p * 16;
        As[kk][m] = Zc[(size_t)(mb + m) * kD + k0 + kk];
      }
      int j = t & 63, kr0 = t >> 6;
#pragma unroll
      for (int p = 0; p < 4; ++p) {
        int kr = kr0 + p * 4;
        Bs[kr][j] = Yc[(size_t)(k0 + kr) * kD + nb + j];
      }
    }
    __syncthreads();
#pragma unroll
    for (int k = 0; k < 16; ++k) {
      float4 a = *(const float4*)&As[k][ty * 4];
      float4 b = *(const float4*)&Bs[k][tx * 4];
      fma16(acc, a, b);
    }
  }
#pragma unroll
  for (int r = 0; r < 4; ++r)
#pragma unroll
    for (int c = 0; c < 4; ++c) {
      int gi = mb + ty * 4 + r, gj = nb + tx * 4 + c;
      T[(size_t)gi * kD + gj] = (gi == gj ? 1.5f : 0.0f) - 0.5f * acc[r][c];
    }
}

// blockIdx.y==0: Yn = Yc @ T ; blockIdx.y==1: Zn = T @ Zc
__global__ void k_ns_yz_r14(const float* __restrict__ Yc, const float* __restrict__ Zc,
                            const float* __restrict__ T, float* __restrict__ Yn,
                            float* __restrict__ Zn) {
  const float* A; const float* B; float* O;
  if (blockIdx.y == 0) { A = Yc; B = T; O = Yn; } else { A = T; B = Zc; O = Zn; }
  __shared__ alignas(16) float As[16][68];
  __shared__ alignas(16) float Bs[16][68];
  int t = threadIdx.x, tx = t & 15, ty = t >> 4;
  int mb = (blockIdx.x >> 2) * 64, nb = (blockIdx.x & 3) * 64;
  float acc[4][4] = {};
  for (int k0 = 0; k0 < 256; k0 += 16) {
    __syncthreads();
    {
      int kk = t & 15, m0 = t >> 4;
#pragma unroll
      for (int p = 0; p < 4; ++p) {
        int m = m0 + p * 16;
        As[kk][m] = A[(size_t)(mb + m) * kD + k0 + kk];
      }
      int j = t & 63, kr0 = t >> 6;
#pragma unroll
      for (int p = 0; p < 4; ++p) {
        int kr = kr0 + p * 4;
        Bs[kr][j] = B[(size_t)(k0 + kr) * kD + nb + j];
      }
    }
    __syncthreads();
#pragma unroll
    for (int k = 0; k < 16; ++k) {
      float4 a = *(const float4*)&As[k][ty * 4];
      float4 b = *(const float4*)&Bs[k][tx * 4];
      fma16(acc, a, b);
    }
  }
#pragma unroll
  for (int r = 0; r < 4; ++r) {
    int gi = mb + ty * 4 + r;
    float4 o = {acc[r][0], acc[r][1], acc[r][2], acc[r][3]};
    *(float4*)&O[(size_t)gi * kD + nb + tx * 4] = o;
  }
}

// M = Zf @ Zf / c
__global__ void k_msq_r14(const float* __restrict__ Zf, const float* __restrict__ cptr,
                          float* __restrict__ M) {
  __shared__ alignas(16) float As[16][68];
  __shared__ alignas(16) float Bs[16][68];
  int t = threadIdx.x, tx = t & 15, ty = t >> 4;
  int mb = (blockIdx.x >> 2) * 64, nb = (blockIdx.x & 3) * 64;
  float acc[4][4] = {};
  for (int k0 = 0; k0 < 256; k0 += 16) {
    __syncthreads();
    {
      int kk = t & 15, m0 = t >> 4;
#pragma unroll
      for (int p = 0; p < 4; ++p) {
        int m = m0 + p * 16;
        As[kk][m] = Zf[(size_t)(mb + m) * kD + k0 + kk];
      }
      int j = t & 63, kr0 = t >> 6;
#pragma unroll
      for (int p = 0; p < 4; ++p) {
        int kr = kr0 + p * 4;
        Bs[kr][j] = Zf[(size_t)(k0 + kr) * kD + nb + j];
      }
    }
    __syncthreads();
#pragma unroll
    for (int k = 0; k < 16; ++k) {
      float4 a = *(const float4*)&As[k][ty * 4];
      float4 b = *(const float4*)&Bs[k][tx * 4];
      fma16(acc, a, b);
    }
  }
  float invc = 1.0f / cptr[0];
#pragma unroll
  for (int r = 0; r < 4; ++r) {
    int gi = mb + ty * 4 + r;
    float4 o = {acc[r][0] * invc, acc[r][1] * invc, acc[r][2] * invc, acc[r][3] * invc};
    *(float4*)&M[(size_t)gi * kD + nb + tx * 4] = o;
  }
}

// G = (Q - mu) @ M   [kNQ x kD]
__global__ void k_G_r14(const float* __restrict__ Q, const float* __restrict__ mu,
                        const float* __restrict__ M, float* __restrict__ G) {
  __shared__ alignas(16) float As[16][68];
  __shared__ alignas(16) float Bs[16][68];
  int t = threadIdx.x, tx = t & 15, ty = t >> 4;
  int nb = blockIdx.x * 64;
  int mb = blockIdx.y * 64;
  float acc[4][4] = {};
  for (int k0 = 0; k0 < 256; k0 += 16) {
    __syncthreads();
    {
      int kk = t & 15, m0 = t >> 4;
      float muk = mu[k0 + kk];
#pragma unroll
      for (int p = 0; p < 4; ++p) {
        int m = m0 + p * 16;
        As[kk][m] = Q[(size_t)(mb + m) * kD + k0 + kk] - muk;
      }
      int j = t & 63, kr0 = t >> 6;
#pragma unroll
      for (int p = 0; p < 4; ++p) {
        int kr = kr0 + p * 4;
        Bs[kr][j] = M[(size_t)(k0 + kr) * kD + nb + j];
      }
    }
    __syncthreads();
#pragma unroll
    for (int k = 0; k < 16; ++k) {
      float4 a = *(const float4*)&As[k][ty * 4];
      float4 b = *(const float4*)&Bs[k][tx * 4];
      fma16(acc, a, b);
    }
  }
#pragma unroll
  for (int r = 0; r < 4; ++r) {
    int gi = mb + ty * 4 + r;
    float4 o = {acc[r][0], acc[r][1], acc[r][2], acc[r][3]};
    *(float4*)&G[(size_t)gi * kD + nb + tx * 4] = o;
  }
}

// q2p[i] = G_i . (Q_i + mu)
__global__ void k_q2p_r14(const float* __restrict__ G, const float* __restrict__ Q,
                          const float* __restrict__ mu, float* __restrict__ q2p) {
  int w = threadIdx.x >> 6, lane = threadIdx.x & 63;
  int row = blockIdx.x * 4 + w;
  float4 g = *(const float4*)&G[(size_t)row * kD + lane * 4];
  float4 q = *(const float4*)&Q[(size_t)row * kD + lane * 4];
  float4 m = *(const float4*)&mu[lane * 4];
  float ss = waveReduceSum(g.x*(q.x+m.x) + g.y*(q.y+m.y) + g.z*(q.z+m.z) + g.w*(q.w+m.w));
  if (lane == 0) q2p[row] = ss;
}

// s2[j] = (S_j - mu) M (S_j - mu), per 64-row chunk
__global__ void k_s2_r14(const float* __restrict__ S, const float* __restrict__ mu,
                         const float* __restrict__ M, float* __restrict__ s2) {
  __shared__ alignas(16) float As[16][68];
  __shared__ alignas(16) float Bs[16][68];
  __shared__ float red[64][17];
  int t = threadIdx.x, tx = t & 15, ty = t >> 4;
  int mb = blockIdx.x * 64;
  float partial[4] = {0.f, 0.f, 0.f, 0.f};
  for (int ntile = 0; ntile < 4; ++ntile) {
    int nb = ntile * 64;
    float acc[4][4] = {};
    for (int k0 = 0; k0 < 256; k0 += 16) {
      __syncthreads();
      {
        int kk = t & 15, m0 = t >> 4;
        float muk = mu[k0 + kk];
#pragma unroll
        for (int p = 0; p < 4; ++p) {
          int m = m0 + p * 16;
          As[kk][m] = S[(size_t)(mb + m) * kD + k0 + kk] - muk;
        }
        int j = t & 63, kr0 = t >> 6;
#pragma unroll
        for (int p = 0; p < 4; ++p) {
          int kr = kr0 + p * 4;
          Bs[kr][j] = M[(size_t)(k0 + kr) * kD + nb + j];
        }
      }
      __syncthreads();
#pragma unroll
      for (int k = 0; k < 16; ++k) {
        float4 a = *(const float4*)&As[k][ty * 4];
        float4 b = *(const float4*)&Bs[k][tx * 4];
        fma16(acc, a, b);
      }
    }
#pragma unroll
    for (int r = 0; r < 4; ++r) {
      int gi = mb + ty * 4 + r;
#pragma unroll
      for (int c = 0; c < 4; ++c) {
        int gj = nb + tx * 4 + c;
        partial[r] += acc[r][c] * (S[(size_t)gi * kD + gj] - mu[gj]);
      }
    }
  }
  __syncthreads();
#pragma unroll
  for (int r = 0; r < 4; ++r) red[ty * 4 + r][tx] = partial[r];
  __syncthreads();
  if (t < 64) {
    float s = 0.f;
#pragma unroll
    for (int x = 0; x < 16; ++x) s += red[t][x];
    s2[mb + t] = s;
  }
}

// GEMM-tiled sampled-median histogram (unchanged from r13)
__global__ void k_median_r14(const float* __restrict__ G, const float* __restrict__ S,
                             const float* __restrict__ q2p, const float* __restrict__ s2,
                             unsigned int* __restrict__ hist, float* __restrict__ ssum) {
  __shared__ alignas(16) float As[16][68];
  __shared__ alignas(16) float Bs[16][68];
  __shared__ unsigned int h[2048];
  __shared__ float fred[4];
  int t = threadIdx.x, tx = t & 15, ty = t >> 4;
  int stile = blockIdx.x, qtile = blockIdx.y;
  for (int i = t; i < 2048; i += 256) h[i] = 0u;

  float acc[4][4] = {};
  for (int k0 = 0; k0 < 256; k0 += 16) {
    __syncthreads();
    {
      int kk = t & 15, m0 = t >> 4;
#pragma unroll
      for (int p = 0; p < 4; ++p) {
        int m = m0 + p * 16;
        As[kk][m] = G[(size_t)((qtile * 64 + m) * 8) * kD + k0 + kk];
        Bs[kk][m] = S[(size_t)((stile * 64 + m) * 8) * kD + k0 + kk];
      }
    }
    __syncthreads();
#pragma unroll
    for (int k = 0; k < 16; ++k) {
      float4 a = *(const float4*)&As[k][ty * 4];
      float4 b = *(const float4*)&Bs[k][tx * 4];
      fma16(acc, a, b);
    }
  }
  float fsum = 0.f;
#pragma unroll
  for (int r = 0; r < 4; ++r) {
    int qi = (qtile * 64 + ty * 4 + r) * 8;
    float q2v = q2p[qi];
#pragma unroll
    for (int c = 0; c < 4; ++c) {
      int sj = (stile * 64 + tx * 4 + c) * 8;
      float d2 = fmaxf(q2v + s2[sj] - 2.0f * acc[r][c], 0.0f);
      fsum += d2;
      int bin = (int)(d2 * 2.0f);
      bin = bin > 2047 ? 2047 : bin;
      atomicAdd(&h[bin], 1u);
    }
  }
  float wsum = waveReduceSum(fsum);
  if ((t & 63) == 0) fred[t >> 6] = wsum;
  __syncthreads();
  if (t == 0) atomicAdd(ssum, fred[0] + fred[1] + fred[2] + fred[3]);
  for (int i = t; i < 2048; i += 256)
    if (h[i]) atomicAdd(&hist[i], h[i]);
}

__global__ void k_gamma_r14(const unsigned int* __restrict__ hist,
                            const float* __restrict__ ssum, float* __restrict__ gptr) {
  if (threadIdx.x != 0) return;
  unsigned long long total = 0;
  for (int i = 0; i < 2048; ++i) total += (unsigned long long)hist[i];
  unsigned long long rr0 = (total - 1) / 2, rr1 = total / 2;
  float v0 = 0.f, v1 = 0.f;
  bool f0 = false, f1 = false;
  unsigned long long cum = 0;
  for (int i = 0; i < 2048; ++i) {
    unsigned int c = hist[i];
    if (!f0 && c > 0 && cum + c > rr0) {
      float frac = (float)(rr0 - cum) + 0.5f;
      v0 = ((float)i + frac / (float)c) * 0.5f;
      f0 = true;
    }
    if (!f1 && c > 0 && cum + c > rr1) {
      float frac = (float)(rr1 - cum) + 0.5f;
      v1 = ((float)i + frac / (float)c) * 0.5f;
      f1 = true;
      break;
    }
    cum += c;
  }
  float med = 0.5f * (v0 + v1);
  float mean = (total > 0) ? (ssum[0] / (float)total) : 1.0f;
  float g = (med > 0.f) ? 1.0f / (med + 1e-6f) : 1.0f / (mean + 1e-6f);
  gptr[0] = g;
}

// MAIN (MFMA): fused cdist^2 + exp + accumulation. Grid (16 s-chunks, 128 q-tiles),
// 256 thr = 4 waves. Each wave: 16-row Q strip x 64 S cols per s-tile.
// A-frag (G rows, bf16) preloaded once; B (S rows, bf16) streamed from L2.
// Layouts (verified, cdna docs): A/B lane holds row[lane&15], k=(lane>>4)*8+j;
// C/D: col=lane&15, row=(lane>>4)*4+reg. No LDS, no barriers.
__global__ void PrototypicalHead_6210522710389_kernel(
    const unsigned short* __restrict__ Gh, const unsigned short* __restrict__ Sh,
    const float* __restrict__ q2p, const float* __restrict__ s2,
    const float* __restrict__ svals, const float* __restrict__ gptr,
    float* __restrict__ part) {
  int t = threadIdx.x;
  int w = t >> 6, lane = t & 63;
  int l15 = lane & 15, quad = lane >> 4;
  int sc = blockIdx.x, qt = blockIdx.y;
  int qbase = qt * 64;
  float gamma = gptr[0];

  // preload A fragments for this wave's 16-row strip (reused over 16 s-tiles)
  int arow = qbase + w * 16 + l15;
  bf16x8 afrag[8];
#pragma unroll
  for (int ks = 0; ks < 8; ++ks)
    afrag[ks] = *(const bf16x8*)&Gh[(size_t)arow * kD + ks * 32 + quad * 8];

  // q2p for my 4 output rows (D row = quad*4 + r within the strip)
  float q2v[4];
#pragma unroll
  for (int r = 0; r < 4; ++r) q2v[r] = q2p[qbase + w * 16 + quad * 4 + r];

  float dAcc[4] = {0.f, 0.f, 0.f, 0.f}, nAcc[4] = {0.f, 0.f, 0.f, 0.f};

  for (int st = 0; st < 16; ++st) {
    int sbase = sc * 1024 + st * 64;
    f32x4 acc0 = {0.f, 0.f, 0.f, 0.f};
    f32x4 acc1 = {0.f, 0.f, 0.f, 0.f};
    f32x4 acc2 = {0.f, 0.f, 0.f, 0.f};
    f32x4 acc3 = {0.f, 0.f, 0.f, 0.f};
    size_t b0 = (size_t)(sbase + 0 * 16 + l15) * kD + quad * 8;
    size_t b1 = (size_t)(sbase + 1 * 16 + l15) * kD + quad * 8;
    size_t b2 = (size_t)(sbase + 2 * 16 + l15) * kD + quad * 8;
    size_t b3 = (size_t)(sbase + 3 * 16 + l15) * kD + quad * 8;
#pragma unroll
    for (int ks = 0; ks < 8; ++ks) {
      bf16x8 f0 = *(const bf16x8*)&Sh[b0 + ks * 32];
      bf16x8 f1 = *(const bf16x8*)&Sh[b1 + ks * 32];
      bf16x8 f2 = *(const bf16x8*)&Sh[b2 + ks * 32];
      bf16x8 f3 = *(const bf16x8*)&Sh[b3 + ks * 32];
      acc0 = __builtin_amdgcn_mfma_f32_16x16x32_bf16(afrag[ks], f0, acc0, 0, 0, 0);
      acc1 = __builtin_amdgcn_mfma_f32_16x16x32_bf16(afrag[ks], f1, acc1, 0, 0, 0);
      acc2 = __builtin_amdgcn_mfma_f32_16x16x32_bf16(afrag[ks], f2, acc2, 0, 0, 0);
      acc3 = __builtin_amdgcn_mfma_f32_16x16x32_bf16(afrag[ks], f3, acc3, 0, 0, 0);
    }
    // epilogue: d2 -> exp -> accumulate (col = l15 within each 16-col tile)
#pragma unroll
    for (int nt = 0; nt < 4; ++nt) {
      f32x4 a = (nt == 0) ? acc0 : (nt == 1) ? acc1 : (nt == 2) ? acc2 : acc3;
      int scol = sbase + nt * 16 + l15;
      float s2v = s2[scol];
      float sv = svals[scol];
#pragma unroll
      for (int r = 0; r < 4; ++r) {
        float d2 = fmaxf(q2v[r] + s2v - 2.0f * a[r], 0.0f);
        float e = __expf(-gamma * d2);
        dAcc[r] += e;
        nAcc[r] += e * sv;
      }
    }
  }
  // reduce across the 16 lanes (l15) sharing each output row
#pragma unroll
  for (int off = 8; off >= 1; off >>= 1) {
#pragma unroll
    for (int r = 0; r < 4; ++r) {
      dAcc[r] += __shfl_xor(dAcc[r], off);
      nAcc[r] += __shfl_xor(nAcc[r], off);
    }
  }
  if (l15 == 0) {
#pragma unroll
    for (int r = 0; r < 4; ++r) {
      size_t q = (size_t)qbase + w * 16 + quad * 4 + r;
      part[(q * 16 + sc) * 2 + 0] = dAcc[r];
      part[(q * 16 + sc) * 2 + 1] = nAcc[r];
    }
  }
}

__global__ void k_final_r14(const float* __restrict__ part, float* __restrict__ out1) {
  int q = blockIdx.x * 256 + threadIdx.x;
  const float* p = part + (size_t)q * 32;
  float d = 0.f, n = 0.f;
#pragma unroll
  for (int i = 0; i < 16; ++i) { d += p[2 * i]; n += p[2 * i + 1]; }
  out1[q] = n / d;
}

extern "C" void kernel_launch(void* const* d_in, const int* in_sizes, int n_in,
                              void* d_out, int out_size, void* d_ws, size_t ws_size,
                              hipStream_t stream) {
  (void)in_sizes; (void)n_in; (void)out_size; (void)ws_size;
  const float* SF = (const float*)d_in[0];   // fp32
  const int*   SL = (const int*)d_in[1];     // int32
  const float* SV = (const float*)d_in[2];   // fp32
  const float* QF = (const float*)d_in[3];   // fp32

  float* ws = (float*)d_ws;
  float* psum  = ws + OFF_PSUM;
  float* pcnt  = ws + OFF_PCNT;
  float* musum = ws + OFF_MUSUM;
  float* xtx   = ws + OFF_XTX;
  unsigned int* hist = (unsigned int*)(ws + OFF_HIST);
  float* ssum  = ws + OFF_SSUM;
  float* protos= ws + OFF_PROTO;
  float* mu    = ws + OFF_MU;
  float* cov   = ws + OFF_COV;
  float* rows  = ws + OFF_ROWS;
  float* cptr  = ws + OFF_C;
  float* gptr  = ws + OFF_C + 1;
  float* Y  = ws + OFF_Y;  float* Z  = ws + OFF_Z;  float* T = ws + OFF_T;
  float* Y2 = ws + OFF_Y2; float* Z2 = ws + OFF_Z2;
  float* M  = ws + OFF_M;
  float* s2 = ws + OFF_S2; float* q2p = ws + OFF_Q2P;
  float* part = ws + OFF_PART;
  float* G = ws + OFF_G;
  unsigned short* Sh = (unsigned short*)(ws + OFF_SH);
  unsigned short* Gh = (unsigned short*)(ws + OFF_GH);

  float* out0 = (float*)d_out;                   // f32 log_probs [8192 x 64]
  float* out1 = out0 + (size_t)kNQ * kC;         // f32 predictions [8192]

  k_zero_r14<<<(int)((ZERO_FLOATS + 255) / 256), 256, 0, stream>>>(ws);

  // bf16 copy of support features (independent of everything else)
  k_tobf16_r14<<<(kNS * kD / 4 + 255) / 256, 256, 0, stream>>>(SF, Sh, kNS * kD / 4);

  // classification
  k_proto_accum_r14<<<kNS / 4, 256, 0, stream>>>(SF, SL, psum, pcnt);
  k_proto_fin_r14<<<kC, 64, 0, stream>>>(psum, pcnt, protos);
  k_logits_r14<<<kNQ, 256, 0, stream>>>(QF, protos, out0);

  // regression: mean, cov
  k_colsum_r14<<<kNS / 64, 256, 0, stream>>>(SF, musum);
  k_mufin_r14<<<1, 256, 0, stream>>>(musum, mu);
  k_xtx_r14<<<dim3(16, 16), 256, 0, stream>>>(SF, xtx);
  k_cov_r14<<<256, 256, 0, stream>>>(xtx, mu, cov);

  // Newton-Schulz inverse sqrt of cov/c (8 coupled iterations)
  k_rowabs_r14<<<256, 64, 0, stream>>>(cov, rows);
  k_cnorm_r14<<<1, 64, 0, stream>>>(rows, cptr);
  k_nsinit_r14<<<256, 256, 0, stream>>>(cov, cptr, Y, Z);
  float *Yc = Y, *Zc = Z, *Yn = Y2, *Zn = Z2;
  for (int it = 0; it < 8; ++it) {
    k_ns_t_r14<<<16, 256, 0, stream>>>(Zc, Yc, T);
    k_ns_yz_r14<<<dim3(16, 2), 256, 0, stream>>>(Yc, Zc, T, Yn, Zn);
    float* tmp = Yc; Yc = Yn; Yn = tmp;
    tmp = Zc; Zc = Zn; Zn = tmp;
  }
  k_msq_r14<<<16, 256, 0, stream>>>(Zc, cptr, M);

  // G = (Q - mu) @ M, bf16 copy, scalar row terms
  k_G_r14<<<dim3(4, kNQ / 64), 256, 0, stream>>>(QF, mu, M, G);
  k_tobf16_r14<<<(kNQ * kD / 4 + 255) / 256, 256, 0, stream>>>(G, Gh, kNQ * kD / 4);
  k_q2p_r14<<<kNQ / 4, 256, 0, stream>>>(G, QF, mu, q2p);
  k_s2_r14<<<kNS / 64, 256, 0, stream>>>(SF, mu, M, s2);

  // sampled median -> gamma
  k_median_r14<<<dim3(32, 16), 256, 0, stream>>>(G, SF, q2p, s2, hist, ssum);
  k_gamma_r14<<<1, 64, 0, stream>>>(hist, ssum, gptr);

  // MFMA fused cdist^2 + softmax numer/denom, then finalize
  PrototypicalHead_6210522710389_kernel<<<dim3(16, 128), 256, 0, stream>>>(
      Gh, Sh, q2p, s2, SV, gptr, part);
  k_final_r14<<<kNQ / 256, 256, 0, stream>>>(part, out1);
}

// Round 15
// 1083.741 us; speedup vs baseline: 3.0022x; 1.2935x over previous
//
#include <hip/hip_runtime.h>
#include <hip/hip_bf16.h>

// Problem dims (fixed by setup_inputs)
constexpr int kNS = 16384;   // support rows
constexpr int kNQ = 8192;    // query rows
constexpr int kD  = 256;     // feature dim
constexpr int kC  = 64;      // classes

// R14 PASSED (1402 us; main MFMA pass 487 us but MfmaUtil 5.8% / VALU 9% ->
// latency-stalled on scattered per-lane B loads: 16x64B L2 transactions per
// load instr). R15: Sh/Gh stored in FRAGMENT-MAJOR swizzled layout (per
// 16-row group: [ks][lane][8], lane=quad*16+l15) so every fragment load is
// a dense 1KB coalesced stream; grid swapped so consecutive blocks share
// the same s-chunk (B reuse in L1/L2).

// ---------------- workspace layout (float offsets into d_ws), ~24.4 MB ----
constexpr size_t OFF_PSUM  = 0;
constexpr size_t OFF_PCNT  = 16384;
constexpr size_t OFF_MUSUM = 16448;
constexpr size_t OFF_XTX   = 16704;
constexpr size_t OFF_HIST  = 82240;
constexpr size_t OFF_SSUM  = 84288;
constexpr size_t ZERO_FLOATS = 84352;
constexpr size_t OFF_PROTO = 84352;
constexpr size_t OFF_MU    = 100736;
constexpr size_t OFF_COV   = 100992;
constexpr size_t OFF_ROWS  = 166528;
constexpr size_t OFF_C     = 166784;
constexpr size_t OFF_Y     = 166800;
constexpr size_t OFF_Z     = 232336;
constexpr size_t OFF_T     = 297872;
constexpr size_t OFF_Y2    = 363408;
constexpr size_t OFF_Z2    = 428944;
constexpr size_t OFF_M     = 494480;
constexpr size_t OFF_S2    = 560016;
constexpr size_t OFF_Q2P   = 576400;
constexpr size_t OFF_PART  = 584592;
constexpr size_t OFF_G     = 846736;     // 8192*256 f32
constexpr size_t OFF_SH    = 2943888;    // 16384*256 bf16 swizzled
constexpr size_t OFF_GH    = 5041040;    // 8192*256 bf16 swizzled

typedef __attribute__((ext_vector_type(8))) short bf16x8;   // 8 bf16 = 4 VGPRs
typedef __attribute__((ext_vector_type(4))) float f32x4;

// f32 -> bf16 (round to nearest even), stored as u16
__device__ __forceinline__ unsigned short f2bf(float f) {
  unsigned int w; __builtin_memcpy(&w, &f, 4);
  unsigned int r = (w + 0x7FFFu + ((w >> 16) & 1u)) >> 16;
  return (unsigned short)r;
}

__device__ __forceinline__ float waveReduceSum(float v) {
#pragma unroll
  for (int off = 32; off > 0; off >>= 1) v += __shfl_xor(v, off);
  return v;
}
__device__ __forceinline__ float waveReduceMax(float v) {
#pragma unroll
  for (int off = 32; off > 0; off >>= 1) v = fmaxf(v, __shfl_xor(v, off));
  return v;
}
__device__ __forceinline__ void fma16(float acc[4][4], float4 a, float4 b) {
  acc[0][0] += a.x*b.x; acc[0][1] += a.x*b.y; acc[0][2] += a.x*b.z; acc[0][3] += a.x*b.w;
  acc[1][0] += a.y*b.x; acc[1][1] += a.y*b.y; acc[1][2] += a.y*b.z; acc[1][3] += a.y*b.w;
  acc[2][0] += a.z*b.x; acc[2][1] += a.z*b.y; acc[2][2] += a.z*b.z; acc[2][3] += a.z*b.w;
  acc[3][0] += a.w*b.x; acc[3][1] += a.w*b.y; acc[3][2] += a.w*b.z; acc[3][3] += a.w*b.w;
}

__global__ void k_zero_r15(float* __restrict__ ws) {
  size_t i = (size_t)blockIdx.x * 256 + threadIdx.x;
  if (i < ZERO_FLOATS) ws[i] = 0.f;
}

// f32 [rows x 256] -> bf16 fragment-major swizzle. One block per 16-row group.
// Group layout: dst[g*4096 + ks*512 + lane*8 + j] = bf16(in[(g*16 + (lane&15))*256
//   + ks*32 + (lane>>4)*8 + j]),  ks in [0,8), lane in [0,64), j in [0,8).
__global__ void k_swz_r15(const float* __restrict__ in, unsigned short* __restrict__ out) {
  int g = blockIdx.x, t = threadIdx.x;
  int ks = t >> 5;                      // 16 dst elems per thread -> ks = t/32
  size_t gbase = (size_t)g * 4096;
#pragma unroll
  for (int f = 0; f < 2; ++f) {
    int lane = (2 * t + f) & 63;
    int q = lane >> 4, r = lane & 15;
    const float* src = &in[(size_t)(g * 16 + r) * kD + ks * 32 + q * 8];
    float4 v0 = *(const float4*)src;
    float4 v1 = *(const float4*)(src + 4);
    ushort4 o0, o1;
    o0.x = f2bf(v0.x); o0.y = f2bf(v0.y); o0.z = f2bf(v0.z); o0.w = f2bf(v0.w);
    o1.x = f2bf(v1.x); o1.y = f2bf(v1.y); o1.z = f2bf(v1.z); o1.w = f2bf(v1.w);
    unsigned short* dst = &out[gbase + (size_t)ks * 512 + (size_t)lane * 8];
    *(ushort4*)dst = o0;
    *(ushort4*)(dst + 4) = o1;
  }
}

// ---------------- classification path ----------------
__global__ void k_proto_accum_r15(const float* __restrict__ X, const int* __restrict__ lab,
                                  float* __restrict__ psum, float* __restrict__ pcnt) {
  int w = threadIdx.x >> 6, lane = threadIdx.x & 63;
  int row = blockIdx.x * 4 + w;
  float4 v = *(const float4*)&X[(size_t)row * kD + lane * 4];
  float ss = waveReduceSum(v.x*v.x + v.y*v.y + v.z*v.z + v.w*v.w);
  float inv = 1.0f / fmaxf(sqrtf(ss), 1e-8f);
  int l = lab[row];
  float* p = psum + (size_t)l * kD + lane * 4;
  atomicAdd(p + 0, v.x * inv); atomicAdd(p + 1, v.y * inv);
  atomicAdd(p + 2, v.z * inv); atomicAdd(p + 3, v.w * inv);
  if (lane == 0) atomicAdd(&pcnt[l], 1.0f);
}

__global__ void k_proto_fin_r15(const float* __restrict__ psum, const float* __restrict__ pcnt,
                                float* __restrict__ protos) {
  int c = blockIdx.x, lane = threadIdx.x;
  float4 v = *(const float4*)&psum[(size_t)c * kD + lane * 4];
  float cnt = fmaxf(pcnt[c], 1.0f);
  v.x /= cnt; v.y /= cnt; v.z /= cnt; v.w /= cnt;
  float ss = waveReduceSum(v.x*v.x + v.y*v.y + v.z*v.z + v.w*v.w);
  float inv = 1.0f / fmaxf(sqrtf(ss), 1e-8f);
  float4 o = {v.x*inv, v.y*inv, v.z*inv, v.w*inv};
  *(float4*)&protos[(size_t)c * kD + lane * 4] = o;
}

__global__ void k_logits_r15(const float* __restrict__ Q, const float* __restrict__ protos,
                             float* __restrict__ out0) {
  __shared__ alignas(16) float qs[kD];
  __shared__ float lg[kC];
  __shared__ float wred[4];
  __shared__ float qis;
  int t = threadIdx.x, w = t >> 6, lane = t & 63;
  int qi = blockIdx.x;
  float myv = Q[(size_t)qi * kD + t];
  qs[t] = myv;
  float ss = waveReduceSum(myv * myv);
  if (lane == 0) wred[w] = ss;
  __syncthreads();
  if (t == 0) qis = 1.0f / fmaxf(sqrtf(wred[0] + wred[1] + wred[2] + wred[3]), 1e-8f);
  __syncthreads();
  float4 qv = *(const float4*)&qs[lane * 4];
  for (int cc = w * 16; cc < w * 16 + 16; ++cc) {
    float4 pv = *(const float4*)&protos[(size_t)cc * kD + lane * 4];
    float d = waveReduceSum(qv.x*pv.x + qv.y*pv.y + qv.z*pv.z + qv.w*pv.w);
    if (lane == 0) lg[cc] = d * qis;
  }
  __syncthreads();
  if (t < 64) {
    float v = lg[t];
    float m = waveReduceMax(v);
    float e = expf(v - m);
    float s = waveReduceSum(e);
    float lse = m + logf(s);
    out0[(size_t)qi * kC + t] = v - lse;
  }
}

// ---------------- regression path ----------------
__global__ void k_colsum_r15(const float* __restrict__ X, float* __restrict__ musum) {
  int t = threadIdx.x;
  int r0 = blockIdx.x * 64;
  float s = 0.f;
  for (int r = 0; r < 64; ++r) s += X[(size_t)(r0 + r) * kD + t];
  atomicAdd(&musum[t], s);
}
__global__ void k_mufin_r15(const float* __restrict__ musum, float* __restrict__ mu) {
  int t = threadIdx.x;
  mu[t] = musum[t] * (1.0f / (float)kNS);
}

__global__ void k_xtx_r15(const float* __restrict__ X, float* __restrict__ xtx) {
  __shared__ alignas(16) float As[16][68];
  __shared__ alignas(16) float Bs[16][68];
  int t = threadIdx.x, tx = t & 15, ty = t >> 4;
  int ab = (blockIdx.x >> 2) * 64, bb = (blockIdx.x & 3) * 64;
  int k0b = blockIdx.y * 1024;
  float acc[4][4] = {};
  for (int k0 = 0; k0 < 1024; k0 += 16) {
    __syncthreads();
    int j = t & 63, kr0 = t >> 6;
#pragma unroll
    for (int p = 0; p < 4; ++p) {
      int kr = kr0 + p * 4;
      size_t base = (size_t)(k0b + k0 + kr) * kD;
      As[kr][j] = X[base + ab + j];
      Bs[kr][j] = X[base + bb + j];
    }
    __syncthreads();
#pragma unroll
    for (int k = 0; k < 16; ++k) {
      float4 a = *(const float4*)&As[k][ty * 4];
      float4 b = *(const float4*)&Bs[k][tx * 4];
      fma16(acc, a, b);
    }
  }
#pragma unroll
  for (int r = 0; r < 4; ++r)
#pragma unroll
    for (int c = 0; c < 4; ++c)
      atomicAdd(&xtx[(size_t)(ab + ty * 4 + r) * kD + bb + tx * 4 + c], acc[r][c]);
}

__global__ void k_cov_r15(const float* __restrict__ xtx, const float* __restrict__ mu,
                          float* __restrict__ cov) {
  int i = blockIdx.x, j = threadIdx.x;
  float v = (xtx[(size_t)i * kD + j] - (float)kNS * mu[i] * mu[j]) * (1.0f / (float)(kNS - 1));
  if (i == j) v += 1e-4f;
  cov[(size_t)i * kD + j] = v;
}

__global__ void k_rowabs_r15(const float* __restrict__ cov, float* __restrict__ rows) {
  int row = blockIdx.x, lane = threadIdx.x;
  float4 v = *(const float4*)&cov[(size_t)row * kD + lane * 4];
  float s = waveReduceSum(fabsf(v.x) + fabsf(v.y) + fabsf(v.z) + fabsf(v.w));
  if (lane == 0) rows[row] = s;
}
__global__ void k_cnorm_r15(const float* __restrict__ rows, float* __restrict__ cptr) {
  int lane = threadIdx.x;
  float m = fmaxf(fmaxf(rows[lane], rows[lane + 64]),
                  fmaxf(rows[lane + 128], rows[lane + 192]));
  m = waveReduceMax(m);
  if (lane == 0) cptr[0] = m;
}
__global__ void k_nsinit_r15(const float* __restrict__ cov, const float* __restrict__ cptr,
                             float* __restrict__ Y, float* __restrict__ Z) {
  int i = blockIdx.x, j = threadIdx.x;
  float invc = 1.0f / cptr[0];
  size_t idx = (size_t)i * kD + j;
  Y[idx] = cov[idx] * invc;
  Z[idx] = (i == j) ? 1.0f : 0.0f;
}

// T = 1.5 I - 0.5 * (Z @ Y)
__global__ void k_ns_t_r15(const float* __restrict__ Zc, const float* __restrict__ Yc,
                           float* __restrict__ T) {
  __shared__ alignas(16) float As[16][68];
  __shared__ alignas(16) float Bs[16][68];
  int t = threadIdx.x, tx = t & 15, ty = t >> 4;
  int mb = (blockIdx.x >> 2) * 64, nb = (blockIdx.x & 3) * 64;
  float acc[4][4] = {};
  for (int k0 = 0; k0 < 256; k0 += 16) {
    __syncthreads();
    {
      int kk = t & 15, m0 = t >> 4;
#pragma unroll
      for (int p = 0; p < 4; ++p) {
        int m = m0 + p * 16;
        As[kk][m] = Zc[(size_t)(mb + m) * kD + k0 + kk];
      }
      int j = t & 63, kr0 = t >> 6;
#pragma unroll
      for (int p = 0; p < 4; ++p) {
        int kr = kr0 + p * 4;
        Bs[kr][j] = Yc[(size_t)(k0 + kr) * kD + nb + j];
      }
    }
    __syncthreads();
#pragma unroll
    for (int k = 0; k < 16; ++k) {
      float4 a = *(const float4*)&As[k][ty * 4];
      float4 b = *(const float4*)&Bs[k][tx * 4];
      fma16(acc, a, b);
    }
  }
#pragma unroll
  for (int r = 0; r < 4; ++r)
#pragma unroll
    for (int c = 0; c < 4; ++c) {
      int gi = mb + ty * 4 + r, gj = nb + tx * 4 + c;
      T[(size_t)gi * kD + gj] = (gi == gj ? 1.5f : 0.0f) - 0.5f * acc[r][c];
    }
}

// blockIdx.y==0: Yn = Yc @ T ; blockIdx.y==1: Zn = T @ Zc
__global__ void k_ns_yz_r15(const float* __restrict__ Yc, const float* __restrict__ Zc,
                            const float* __restrict__ T, float* __restrict__ Yn,
                            float* __restrict__ Zn) {
  const float* A; const float* B; float* O;
  if (blockIdx.y == 0) { A = Yc; B = T; O = Yn; } else { A = T; B = Zc; O = Zn; }
  __shared__ alignas(16) float As[16][68];
  __shared__ alignas(16) float Bs[16][68];
  int t = threadIdx.x, tx = t & 15, ty = t >> 4;
  int mb = (blockIdx.x >> 2) * 64, nb = (blockIdx.x & 3) * 64;
  float acc[4][4] = {};
  for (int k0 = 0; k0 < 256; k0 += 16) {
    __syncthreads();
    {
      int kk = t & 15, m0 = t >> 4;
#pragma unroll
      for (int p = 0; p < 4; ++p) {
        int m = m0 + p * 16;
        As[kk][m] = A[(size_t)(mb + m) * kD + k0 + kk];
      }
      int j = t & 63, kr0 = t >> 6;
#pragma unroll
      for (int p = 0; p < 4; ++p) {
        int kr = kr0 + p * 4;
        Bs[kr][j] = B[(size_t)(k0 + kr) * kD + nb + j];
      }
    }
    __syncthreads();
#pragma unroll
    for (int k = 0; k < 16; ++k) {
      float4 a = *(const float4*)&As[k][ty * 4];
      float4 b = *(const float4*)&Bs[k][tx * 4];
      fma16(acc, a, b);
    }
  }
#pragma unroll
  for (int r = 0; r < 4; ++r) {
    int gi = mb + ty * 4 + r;
    float4 o = {acc[r][0], acc[r][1], acc[r][2], acc[r][3]};
    *(float4*)&O[(size_t)gi * kD + nb + tx * 4] = o;
  }
}

// M = Zf @ Zf / c
__global__ void k_msq_r15(const float* __restrict__ Zf, const float* __restrict__ cptr,
                          float* __restrict__ M) {
  __shared__ alignas(16) float As[16][68];
  __shared__ alignas(16) float Bs[16][68];
  int t = threadIdx.x, tx = t & 15, ty = t >> 4;
  int mb = (blockIdx.x >> 2) * 64, nb = (blockIdx.x & 3) * 64;
  float acc[4][4] = {};
  for (int k0 = 0; k0 < 256; k0 += 16) {
    __syncthreads();
    {
      int kk = t & 15, m0 = t >> 4;
#pragma unroll
      for (int p = 0; p < 4; ++p) {
        int m = m0 + p * 16;
        As[kk][m] = Zf[(size_t)(mb + m) * kD + k0 + kk];
      }
      int j = t & 63, kr0 = t >> 6;
#pragma unroll
      for (int p = 0; p < 4; ++p) {
        int kr = kr0 + p * 4;
        Bs[kr][j] = Zf[(size_t)(k0 + kr) * kD + nb + j];
      }
    }
    __syncthreads();
#pragma unroll
    for (int k = 0; k < 16; ++k) {
      float4 a = *(const float4*)&As[k][ty * 4];
      float4 b = *(const float4*)&Bs[k][tx * 4];
      fma16(acc, a, b);
    }
  }
  float invc = 1.0f / cptr[0];
#pragma unroll
  for (int r = 0; r < 4; ++r) {
    int gi = mb + ty * 4 + r;
    float4 o = {acc[r][0] * invc, acc[r][1] * invc, acc[r][2] * invc, acc[r][3] * invc};
    *(float4*)&M[(size_t)gi * kD + nb + tx * 4] = o;
  }
}

// G = (Q - mu) @ M   [kNQ x kD]
__global__ void k_G_r15(const float* __restrict__ Q, const float* __restrict__ mu,
                        const float* __restrict__ M, float* __restrict__ G) {
  __shared__ alignas(16) float As[16][68];
  __shared__ alignas(16) float Bs[16][68];
  int t = threadIdx.x, tx = t & 15, ty = t >> 4;
  int nb = blockIdx.x * 64;
  int mb = blockIdx.y * 64;
  float acc[4][4] = {};
  for (int k0 = 0; k0 < 256; k0 += 16) {
    __syncthreads();
    {
      int kk = t & 15, m0 = t >> 4;
      float muk = mu[k0 + kk];
#pragma unroll
      for (int p = 0; p < 4; ++p) {
        int m = m0 + p * 16;
        As[kk][m] = Q[(size_t)(mb + m) * kD + k0 + kk] - muk;
      }
      int j = t & 63, kr0 = t >> 6;
#pragma unroll
      for (int p = 0; p < 4; ++p) {
        int kr = kr0 + p * 4;
        Bs[kr][j] = M[(size_t)(k0 + kr) * kD + nb + j];
      }
    }
    __syncthreads();
#pragma unroll
    for (int k = 0; k < 16; ++k) {
      float4 a = *(const float4*)&As[k][ty * 4];
      float4 b = *(const float4*)&Bs[k][tx * 4];
      fma16(acc, a, b);
    }
  }
#pragma unroll
  for (int r = 0; r < 4; ++r) {
    int gi = mb + ty * 4 + r;
    float4 o = {acc[r][0], acc[r][1], acc[r][2], acc[r][3]};
    *(float4*)&G[(size_t)gi * kD + nb + tx * 4] = o;
  }
}

// q2p[i] = G_i . (Q_i + mu)
__global__ void k_q2p_r15(const float* __restrict__ G, const float* __restrict__ Q,
                          const float* __restrict__ mu, float* __restrict__ q2p) {
  int w = threadIdx.x >> 6, lane = threadIdx.x & 63;
  int row = blockIdx.x * 4 + w;
  float4 g = *(const float4*)&G[(size_t)row * kD + lane * 4];
  float4 q = *(const float4*)&Q[(size_t)row * kD + lane * 4];
  float4 m = *(const float4*)&mu[lane * 4];
  float ss = waveReduceSum(g.x*(q.x+m.x) + g.y*(q.y+m.y) + g.z*(q.z+m.z) + g.w*(q.w+m.w));
  if (lane == 0) q2p[row] = ss;
}

// s2[j] = (S_j - mu) M (S_j - mu), per 64-row chunk
__global__ void k_s2_r15(const float* __restrict__ S, const float* __restrict__ mu,
                         const float* __restrict__ M, float* __restrict__ s2) {
  __shared__ alignas(16) float As[16][68];
  __shared__ alignas(16) float Bs[16][68];
  __shared__ float red[64][17];
  int t = threadIdx.x, tx = t & 15, ty = t >> 4;
  int mb = blockIdx.x * 64;
  float partial[4] = {0.f, 0.f, 0.f, 0.f};
  for (int ntile = 0; ntile < 4; ++ntile) {
    int nb = ntile * 64;
    float acc[4][4] = {};
    for (int k0 = 0; k0 < 256; k0 += 16) {
      __syncthreads();
      {
        int kk = t & 15, m0 = t >> 4;
        float muk = mu[k0 + kk];
#pragma unroll
        for (int p = 0; p < 4; ++p) {
          int m = m0 + p * 16;
          As[kk][m] = S[(size_t)(mb + m) * kD + k0 + kk] - muk;
        }
        int j = t & 63, kr0 = t >> 6;
#pragma unroll
        for (int p = 0; p < 4; ++p) {
          int kr = kr0 + p * 4;
          Bs[kr][j] = M[(size_t)(k0 + kr) * kD + nb + j];
        }
      }
      __syncthreads();
#pragma unroll
      for (int k = 0; k < 16; ++k) {
        float4 a = *(const float4*)&As[k][ty * 4];
        float4 b = *(const float4*)&Bs[k][tx * 4];
        fma16(acc, a, b);
      }
    }
#pragma unroll
    for (int r = 0; r < 4; ++r) {
      int gi = mb + ty * 4 + r;
#pragma unroll
      for (int c = 0; c < 4; ++c) {
        int gj = nb + tx * 4 + c;
        partial[r] += acc[r][c] * (S[(size_t)gi * kD + gj] - mu[gj]);
      }
    }
  }
  __syncthreads();
#pragma unroll
  for (int r = 0; r < 4; ++r) red[ty * 4 + r][tx] = partial[r];
  __syncthreads();
  if (t < 64) {
    float s = 0.f;
#pragma unroll
    for (int x = 0; x < 16; ++x) s += red[t][x];
    s2[mb + t] = s;
  }
}

// GEMM-tiled sampled-median histogram
__global__ void k_median_r15(const float* __restrict__ G, const float* __restrict__ S,
                             const float* __restrict__ q2p, const float* __restrict__ s2,
                             unsigned int* __restrict__ hist, float* __restrict__ ssum) {
  __shared__ alignas(16) float As[16][68];
  __shared__ alignas(16) float Bs[16][68];
  __shared__ unsigned int h[2048];
  __shared__ float fred[4];
  int t = threadIdx.x, tx = t & 15, ty = t >> 4;
  int stile = blockIdx.x, qtile = blockIdx.y;
  for (int i = t; i < 2048; i += 256) h[i] = 0u;

  float acc[4][4] = {};
  for (int k0 = 0; k0 < 256; k0 += 16) {
    __syncthreads();
    {
      int kk = t & 15, m0 = t >> 4;
#pragma unroll
      for (int p = 0; p < 4; ++p) {
        int m = m0 + p * 16;
        As[kk][m] = G[(size_t)((qtile * 64 + m) * 8) * kD + k0 + kk];
        Bs[kk][m] = S[(size_t)((stile * 64 + m) * 8) * kD + k0 + kk];
      }
    }
    __syncthreads();
#pragma unroll
    for (int k = 0; k < 16; ++k) {
      float4 a = *(const float4*)&As[k][ty * 4];
      float4 b = *(const float4*)&Bs[k][tx * 4];
      fma16(acc, a, b);
    }
  }
  float fsum = 0.f;
#pragma unroll
  for (int r = 0; r < 4; ++r) {
    int qi = (qtile * 64 + ty * 4 + r) * 8;
    float q2v = q2p[qi];
#pragma unroll
    for (int c = 0; c < 4; ++c) {
      int sj = (stile * 64 + tx * 4 + c) * 8;
      float d2 = fmaxf(q2v + s2[sj] - 2.0f * acc[r][c], 0.0f);
      fsum += d2;
      int bin = (int)(d2 * 2.0f);
      bin = bin > 2047 ? 2047 : bin;
      atomicAdd(&h[bin], 1u);
    }
  }
  float wsum = waveReduceSum(fsum);
  if ((t & 63) == 0) fred[t >> 6] = wsum;
  __syncthreads();
  if (t == 0) atomicAdd(ssum, fred[0] + fred[1] + fred[2] + fred[3]);
  for (int i = t; i < 2048; i += 256)
    if (h[i]) atomicAdd(&hist[i], h[i]);
}

__global__ void k_gamma_r15(const unsigned int* __restrict__ hist,
                            const float* __restrict__ ssum, float* __restrict__ gptr) {
  if (threadIdx.x != 0) return;
  unsigned long long total = 0;
  for (int i = 0; i < 2048; ++i) total += (unsigned long long)hist[i];
  unsigned long long rr0 = (total - 1) / 2, rr1 = total / 2;
  float v0 = 0.f, v1 = 0.f;
  bool f0 = false, f1 = false;
  unsigned long long cum = 0;
  for (int i = 0; i < 2048; ++i) {
    unsigned int c = hist[i];
    if (!f0 && c > 0 && cum + c > rr0) {
      float frac = (float)(rr0 - cum) + 0.5f;
      v0 = ((float)i + frac / (float)c) * 0.5f;
      f0 = true;
    }
    if (!f1 && c > 0 && cum + c > rr1) {
      float frac = (float)(rr1 - cum) + 0.5f;
      v1 = ((float)i + frac / (float)c) * 0.5f;
      f1 = true;
      break;
    }
    cum += c;
  }
  float med = 0.5f * (v0 + v1);
  float mean = (total > 0) ? (ssum[0] / (float)total) : 1.0f;
  float g = (med > 0.f) ? 1.0f / (med + 1e-6f) : 1.0f / (mean + 1e-6f);
  gptr[0] = g;
}

// MAIN (MFMA, swizzled operands): grid (128 q-tiles, 16 s-chunks).
// Fragment load = base + lane*8 -> fully coalesced 1KB per instruction.
__global__ void PrototypicalHead_6210522710389_kernel(
    const unsigned short* __restrict__ Gh, const unsigned short* __restrict__ Sh,
    const float* __restrict__ q2p, const float* __restrict__ s2,
    const float* __restrict__ svals, const float* __restrict__ gptr,
    float* __restrict__ part) {
  int t = threadIdx.x;
  int w = t >> 6, lane = t & 63;
  int l15 = lane & 15, quad = lane >> 4;
  int qt = blockIdx.x, sc = blockIdx.y;
  int qbase = qt * 64;
  float gamma = gptr[0];

  // preload A fragments (swizzled group qt*4 + w), reused over all 16 s-tiles
  size_t agrp = (size_t)(qt * 4 + w) * 4096;
  bf16x8 afrag[8];
#pragma unroll
  for (int ks = 0; ks < 8; ++ks)
    afrag[ks] = *(const bf16x8*)&Gh[agrp + (size_t)ks * 512 + (size_t)lane * 8];

  float q2v[4];
#pragma unroll
  for (int r = 0; r < 4; ++r) q2v[r] = q2p[qbase + w * 16 + quad * 4 + r];

  float dAcc[4] = {0.f, 0.f, 0.f, 0.f}, nAcc[4] = {0.f, 0.f, 0.f, 0.f};

  for (int st = 0; st < 16; ++st) {
    int sbase = sc * 1024 + st * 64;
    int sgrp = sbase >> 4;                        // 16-row group index
    f32x4 acc0 = {0.f, 0.f, 0.f, 0.f};
    f32x4 acc1 = {0.f, 0.f, 0.f, 0.f};
    f32x4 acc2 = {0.f, 0.f, 0.f, 0.f};
    f32x4 acc3 = {0.f, 0.f, 0.f, 0.f};
    const unsigned short* B0 = &Sh[(size_t)(sgrp + 0) * 4096 + (size_t)lane * 8];
    const unsigned short* B1 = &Sh[(size_t)(sgrp + 1) * 4096 + (size_t)lane * 8];
    const unsigned short* B2 = &Sh[(size_t)(sgrp + 2) * 4096 + (size_t)lane * 8];
    const unsigned short* B3 = &Sh[(size_t)(sgrp + 3) * 4096 + (size_t)lane * 8];
#pragma unroll
    for (int ks = 0; ks < 8; ++ks) {
      bf16x8 f0 = *(const bf16x8*)(B0 + ks * 512);
      bf16x8 f1 = *(const bf16x8*)(B1 + ks * 512);
      bf16x8 f2 = *(const bf16x8*)(B2 + ks * 512);
      bf16x8 f3 = *(const bf16x8*)(B3 + ks * 512);
      acc0 = __builtin_amdgcn_mfma_f32_16x16x32_bf16(afrag[ks], f0, acc0, 0, 0, 0);
      acc1 = __builtin_amdgcn_mfma_f32_16x16x32_bf16(afrag[ks], f1, acc1, 0, 0, 0);
      acc2 = __builtin_amdgcn_mfma_f32_16x16x32_bf16(afrag[ks], f2, acc2, 0, 0, 0);
      acc3 = __builtin_amdgcn_mfma_f32_16x16x32_bf16(afrag[ks], f3, acc3, 0, 0, 0);
    }
#pragma unroll
    for (int nt = 0; nt < 4; ++nt) {
      f32x4 a = (nt == 0) ? acc0 : (nt == 1) ? acc1 : (nt == 2) ? acc2 : acc3;
      int scol = sbase + nt * 16 + l15;
      float s2v = s2[scol];
      float sv = svals[scol];
#pragma unroll
      for (int r = 0; r < 4; ++r) {
        float d2 = fmaxf(q2v[r] + s2v - 2.0f * a[r], 0.0f);
        float e = __expf(-gamma * d2);
        dAcc[r] += e;
        nAcc[r] += e * sv;
      }
    }
  }
#pragma unroll
  for (int off = 8; off >= 1; off >>= 1) {
#pragma unroll
    for (int r = 0; r < 4; ++r) {
      dAcc[r] += __shfl_xor(dAcc[r], off);
      nAcc[r] += __shfl_xor(nAcc[r], off);
    }
  }
  if (l15 == 0) {
#pragma unroll
    for (int r = 0; r < 4; ++r) {
      size_t q = (size_t)qbase + w * 16 + quad * 4 + r;
      part[(q * 16 + sc) * 2 + 0] = dAcc[r];
      part[(q * 16 + sc) * 2 + 1] = nAcc[r];
    }
  }
}

__global__ void k_final_r15(const float* __restrict__ part, float* __restrict__ out1) {
  int q = blockIdx.x * 256 + threadIdx.x;
  const float* p = part + (size_t)q * 32;
  float d = 0.f, n = 0.f;
#pragma unroll
  for (int i = 0; i < 16; ++i) { d += p[2 * i]; n += p[2 * i + 1]; }
  out1[q] = n / d;
}

extern "C" void kernel_launch(void* const* d_in, const int* in_sizes, int n_in,
                              void* d_out, int out_size, void* d_ws, size_t ws_size,
                              hipStream_t stream) {
  (void)in_sizes; (void)n_in; (void)out_size; (void)ws_size;
  const float* SF = (const float*)d_in[0];   // fp32
  const int*   SL = (const int*)d_in[1];     // int32
  const float* SV = (const float*)d_in[2];   // fp32
  const float* QF = (const float*)d_in[3];   // fp32

  float* ws = (float*)d_ws;
  float* psum  = ws + OFF_PSUM;
  float* pcnt  = ws + OFF_PCNT;
  float* musum = ws + OFF_MUSUM;
  float* xtx   = ws + OFF_XTX;
  unsigned int* hist = (unsigned int*)(ws + OFF_HIST);
  float* ssum  = ws + OFF_SSUM;
  float* protos= ws + OFF_PROTO;
  float* mu    = ws + OFF_MU;
  float* cov   = ws + OFF_COV;
  float* rows  = ws + OFF_ROWS;
  float* cptr  = ws + OFF_C;
  float* gptr  = ws + OFF_C + 1;
  float* Y  = ws + OFF_Y;  float* Z  = ws + OFF_Z;  float* T = ws + OFF_T;
  float* Y2 = ws + OFF_Y2; float* Z2 = ws + OFF_Z2;
  float* M  = ws + OFF_M;
  float* s2 = ws + OFF_S2; float* q2p = ws + OFF_Q2P;
  float* part = ws + OFF_PART;
  float* G = ws + OFF_G;
  unsigned short* Sh = (unsigned short*)(ws + OFF_SH);
  unsigned short* Gh = (unsigned short*)(ws + OFF_GH);

  float* out0 = (float*)d_out;                   // f32 log_probs [8192 x 64]
  float* out1 = out0 + (size_t)kNQ * kC;         // f32 predictions [8192]

  k_zero_r15<<<(int)((ZERO_FLOATS + 255) / 256), 256, 0, stream>>>(ws);

  // swizzled bf16 copy of support features
  k_swz_r15<<<kNS / 16, 256, 0, stream>>>(SF, Sh);

  // classification
  k_proto_accum_r15<<<kNS / 4, 256, 0, stream>>>(SF, SL, psum, pcnt);
  k_proto_fin_r15<<<kC, 64, 0, stream>>>(psum, pcnt, protos);
  k_logits_r15<<<kNQ, 256, 0, stream>>>(QF, protos, out0);

  // regression: mean, cov
  k_colsum_r15<<<kNS / 64, 256, 0, stream>>>(SF, musum);
  k_mufin_r15<<<1, 256, 0, stream>>>(musum, mu);
  k_xtx_r15<<<dim3(16, 16), 256, 0, stream>>>(SF, xtx);
  k_cov_r15<<<256, 256, 0, stream>>>(xtx, mu, cov);

  // Newton-Schulz inverse sqrt of cov/c (8 coupled iterations)
  k_rowabs_r15<<<256, 64, 0, stream>>>(cov, rows);
  k_cnorm_r15<<<1, 64, 0, stream>>>(rows, cptr);
  k_nsinit_r15<<<256, 256, 0, stream>>>(cov, cptr, Y, Z);
  float *Yc = Y, *Zc = Z, *Yn = Y2, *Zn = Z2;
  for (int it = 0; it < 8; ++it) {
    k_ns_t_r15<<<16, 256, 0, stream>>>(Zc, Yc, T);
    k_ns_yz_r15<<<dim3(16, 2), 256, 0, stream>>>(Yc, Zc, T, Yn, Zn);
    float* tmp = Yc; Yc = Yn; Yn = tmp;
    tmp = Zc; Zc = Zn; Zn = tmp;
  }
  k_msq_r15<<<16, 256, 0, stream>>>(Zc, cptr, M);

  // G = (Q - mu) @ M, swizzled bf16 copy, scalar row terms
  k_G_r15<<<dim3(4, kNQ / 64), 256, 0, stream>>>(QF, mu, M, G);
  k_swz_r15<<<kNQ / 16, 256, 0, stream>>>(G, Gh);
  k_q2p_r15<<<kNQ / 4, 256, 0, stream>>>(G, QF, mu, q2p);
  k_s2_r15<<<kNS / 64, 256, 0, stream>>>(SF, mu, M, s2);

  // sampled median -> gamma
  k_median_r15<<<dim3(32, 16), 256, 0, stream>>>(G, SF, q2p, s2, hist, ssum);
  k_gamma_r15<<<1, 64, 0, stream>>>(hist, ssum, gptr);

  // MFMA fused cdist^2 + softmax numer/denom, then finalize
  PrototypicalHead_6210522710389_kernel<<<dim3(128, 16), 256, 0, stream>>>(
      Gh, Sh, q2p, s2, SV, gptr, part);
  k_final_r15<<<kNQ / 256, 256, 0, stream>>>(part, out1);
}

// Round 16
// 753.120 us; speedup vs baseline: 4.3202x; 1.4390x over previous
//
#include <hip/hip_runtime.h>
#include <hip/hip_bf16.h>

// Problem dims (fixed by setup_inputs)
constexpr int kNS = 16384;   // support rows
constexpr int kNQ = 8192;    // query rows
constexpr int kD  = 256;     // feature dim
constexpr int kC  = 64;      // classes

// R15 PASSED (1084 us). Top kernel was k_gamma (171 us, SINGLE-THREAD serial
// bin scan). R16: (1) parallel k_gamma (256 thr + LDS scan, ~3 us);
// (2) NS-sqrt chain replaced by direct Newton INVERSE X<-X(2I-covX), 6 iters
// (we only ever use cov^-1), matmuls as row-per-block (256 blocks, ~5 us).

// ---------------- workspace layout (float offsets into d_ws), ~24.4 MB ----
constexpr size_t OFF_PSUM  = 0;
constexpr size_t OFF_PCNT  = 16384;
constexpr size_t OFF_MUSUM = 16448;
constexpr size_t OFF_XTX   = 16704;
constexpr size_t OFF_HIST  = 82240;
constexpr size_t OFF_SSUM  = 84288;
constexpr size_t ZERO_FLOATS = 84352;
constexpr size_t OFF_PROTO = 84352;
constexpr size_t OFF_MU    = 100736;
constexpr size_t OFF_COV   = 100992;
constexpr size_t OFF_ROWS  = 166528;
constexpr size_t OFF_C     = 166784;
constexpr size_t OFF_Y     = 166800;     // Newton X ping
constexpr size_t OFF_T     = 297872;     // Newton T
constexpr size_t OFF_Y2    = 363408;     // Newton X pong
constexpr size_t OFF_S2    = 560016;
constexpr size_t OFF_Q2P   = 576400;
constexpr size_t OFF_PART  = 584592;
constexpr size_t OFF_G     = 846736;     // 8192*256 f32
constexpr size_t OFF_SH    = 2943888;    // 16384*256 bf16 swizzled
constexpr size_t OFF_GH    = 5041040;    // 8192*256 bf16 swizzled

typedef __attribute__((ext_vector_type(8))) short bf16x8;
typedef __attribute__((ext_vector_type(4))) float f32x4;

__device__ __forceinline__ unsigned short f2bf(float f) {
  unsigned int w; __builtin_memcpy(&w, &f, 4);
  unsigned int r = (w + 0x7FFFu + ((w >> 16) & 1u)) >> 16;
  return (unsigned short)r;
}

__device__ __forceinline__ float waveReduceSum(float v) {
#pragma unroll
  for (int off = 32; off > 0; off >>= 1) v += __shfl_xor(v, off);
  return v;
}
__device__ __forceinline__ float waveReduceMax(float v) {
#pragma unroll
  for (int off = 32; off > 0; off >>= 1) v = fmaxf(v, __shfl_xor(v, off));
  return v;
}
__device__ __forceinline__ void fma16(float acc[4][4], float4 a, float4 b) {
  acc[0][0] += a.x*b.x; acc[0][1] += a.x*b.y; acc[0][2] += a.x*b.z; acc[0][3] += a.x*b.w;
  acc[1][0] += a.y*b.x; acc[1][1] += a.y*b.y; acc[1][2] += a.y*b.z; acc[1][3] += a.y*b.w;
  acc[2][0] += a.z*b.x; acc[2][1] += a.z*b.y; acc[2][2] += a.z*b.z; acc[2][3] += a.z*b.w;
  acc[3][0] += a.w*b.x; acc[3][1] += a.w*b.y; acc[3][2] += a.w*b.z; acc[3][3] += a.w*b.w;
}

__global__ void k_zero_r16(float* __restrict__ ws) {
  size_t i = (size_t)blockIdx.x * 256 + threadIdx.x;
  if (i < ZERO_FLOATS) ws[i] = 0.f;
}

// f32 [rows x 256] -> bf16 fragment-major swizzle (one block per 16-row group)
__global__ void k_swz_r16(const float* __restrict__ in, unsigned short* __restrict__ out) {
  int g = blockIdx.x, t = threadIdx.x;
  int ks = t >> 5;
  size_t gbase = (size_t)g * 4096;
#pragma unroll
  for (int f = 0; f < 2; ++f) {
    int lane = (2 * t + f) & 63;
    int q = lane >> 4, r = lane & 15;
    const float* src = &in[(size_t)(g * 16 + r) * kD + ks * 32 + q * 8];
    float4 v0 = *(const float4*)src;
    float4 v1 = *(const float4*)(src + 4);
    ushort4 o0, o1;
    o0.x = f2bf(v0.x); o0.y = f2bf(v0.y); o0.z = f2bf(v0.z); o0.w = f2bf(v0.w);
    o1.x = f2bf(v1.x); o1.y = f2bf(v1.y); o1.z = f2bf(v1.z); o1.w = f2bf(v1.w);
    unsigned short* dst = &out[gbase + (size_t)ks * 512 + (size_t)lane * 8];
    *(ushort4*)dst = o0;
    *(ushort4*)(dst + 4) = o1;
  }
}

// ---------------- classification path ----------------
__global__ void k_proto_accum_r16(const float* __restrict__ X, const int* __restrict__ lab,
                                  float* __restrict__ psum, float* __restrict__ pcnt) {
  int w = threadIdx.x >> 6, lane = threadIdx.x & 63;
  int row = blockIdx.x * 4 + w;
  float4 v = *(const float4*)&X[(size_t)row * kD + lane * 4];
  float ss = waveReduceSum(v.x*v.x + v.y*v.y + v.z*v.z + v.w*v.w);
  float inv = 1.0f / fmaxf(sqrtf(ss), 1e-8f);
  int l = lab[row];
  float* p = psum + (size_t)l * kD + lane * 4;
  atomicAdd(p + 0, v.x * inv); atomicAdd(p + 1, v.y * inv);
  atomicAdd(p + 2, v.z * inv); atomicAdd(p + 3, v.w * inv);
  if (lane == 0) atomicAdd(&pcnt[l], 1.0f);
}

__global__ void k_proto_fin_r16(const float* __restrict__ psum, const float* __restrict__ pcnt,
                                float* __restrict__ protos) {
  int c = blockIdx.x, lane = threadIdx.x;
  float4 v = *(const float4*)&psum[(size_t)c * kD + lane * 4];
  float cnt = fmaxf(pcnt[c], 1.0f);
  v.x /= cnt; v.y /= cnt; v.z /= cnt; v.w /= cnt;
  float ss = waveReduceSum(v.x*v.x + v.y*v.y + v.z*v.z + v.w*v.w);
  float inv = 1.0f / fmaxf(sqrtf(ss), 1e-8f);
  float4 o = {v.x*inv, v.y*inv, v.z*inv, v.w*inv};
  *(float4*)&protos[(size_t)c * kD + lane * 4] = o;
}

__global__ void k_logits_r16(const float* __restrict__ Q, const float* __restrict__ protos,
                             float* __restrict__ out0) {
  __shared__ alignas(16) float qs[kD];
  __shared__ float lg[kC];
  __shared__ float wred[4];
  __shared__ float qis;
  int t = threadIdx.x, w = t >> 6, lane = t & 63;
  int qi = blockIdx.x;
  float myv = Q[(size_t)qi * kD + t];
  qs[t] = myv;
  float ss = waveReduceSum(myv * myv);
  if (lane == 0) wred[w] = ss;
  __syncthreads();
  if (t == 0) qis = 1.0f / fmaxf(sqrtf(wred[0] + wred[1] + wred[2] + wred[3]), 1e-8f);
  __syncthreads();
  float4 qv = *(const float4*)&qs[lane * 4];
  for (int cc = w * 16; cc < w * 16 + 16; ++cc) {
    float4 pv = *(const float4*)&protos[(size_t)cc * kD + lane * 4];
    float d = waveReduceSum(qv.x*pv.x + qv.y*pv.y + qv.z*pv.z + qv.w*pv.w);
    if (lane == 0) lg[cc] = d * qis;
  }
  __syncthreads();
  if (t < 64) {
    float v = lg[t];
    float m = waveReduceMax(v);
    float e = expf(v - m);
    float s = waveReduceSum(e);
    float lse = m + logf(s);
    out0[(size_t)qi * kC + t] = v - lse;
  }
}

// ---------------- regression path ----------------
__global__ void k_colsum_r16(const float* __restrict__ X, float* __restrict__ musum) {
  int t = threadIdx.x;
  int r0 = blockIdx.x * 64;
  float s = 0.f;
  for (int r = 0; r < 64; ++r) s += X[(size_t)(r0 + r) * kD + t];
  atomicAdd(&musum[t], s);
}
__global__ void k_mufin_r16(const float* __restrict__ musum, float* __restrict__ mu) {
  int t = threadIdx.x;
  mu[t] = musum[t] * (1.0f / (float)kNS);
}

__global__ void k_xtx_r16(const float* __restrict__ X, float* __restrict__ xtx) {
  __shared__ alignas(16) float As[16][68];
  __shared__ alignas(16) float Bs[16][68];
  int t = threadIdx.x, tx = t & 15, ty = t >> 4;
  int ab = (blockIdx.x >> 2) * 64, bb = (blockIdx.x & 3) * 64;
  int k0b = blockIdx.y * 1024;
  float acc[4][4] = {};
  for (int k0 = 0; k0 < 1024; k0 += 16) {
    __syncthreads();
    int j = t & 63, kr0 = t >> 6;
#pragma unroll
    for (int p = 0; p < 4; ++p) {
      int kr = kr0 + p * 4;
      size_t base = (size_t)(k0b + k0 + kr) * kD;
      As[kr][j] = X[base + ab + j];
      Bs[kr][j] = X[base + bb + j];
    }
    __syncthreads();
#pragma unroll
    for (int k = 0; k < 16; ++k) {
      float4 a = *(const float4*)&As[k][ty * 4];
      float4 b = *(const float4*)&Bs[k][tx * 4];
      fma16(acc, a, b);
    }
  }
#pragma unroll
  for (int r = 0; r < 4; ++r)
#pragma unroll
    for (int c = 0; c < 4; ++c)
      atomicAdd(&xtx[(size_t)(ab + ty * 4 + r) * kD + bb + tx * 4 + c], acc[r][c]);
}

__global__ void k_cov_r16(const float* __restrict__ xtx, const float* __restrict__ mu,
                          float* __restrict__ cov) {
  int i = blockIdx.x, j = threadIdx.x;
  float v = (xtx[(size_t)i * kD + j] - (float)kNS * mu[i] * mu[j]) * (1.0f / (float)(kNS - 1));
  if (i == j) v += 1e-4f;
  cov[(size_t)i * kD + j] = v;
}

__global__ void k_rowabs_r16(const float* __restrict__ cov, float* __restrict__ rows) {
  int row = blockIdx.x, lane = threadIdx.x;
  float4 v = *(const float4*)&cov[(size_t)row * kD + lane * 4];
  float s = waveReduceSum(fabsf(v.x) + fabsf(v.y) + fabsf(v.z) + fabsf(v.w));
  if (lane == 0) rows[row] = s;
}
__global__ void k_cnorm_r16(const float* __restrict__ rows, float* __restrict__ cptr) {
  int lane = threadIdx.x;
  float m = fmaxf(fmaxf(rows[lane], rows[lane + 64]),
                  fmaxf(rows[lane + 128], rows[lane + 192]));
  m = waveReduceMax(m);
  if (lane == 0) cptr[0] = m;
}
// X0 = I / c
__global__ void k_newt_init_r16(const float* __restrict__ cptr, float* __restrict__ X) {
  int i = blockIdx.x, j = threadIdx.x;
  X[(size_t)i * kD + j] = (i == j) ? (1.0f / cptr[0]) : 0.0f;
}

// T = 2I - cov @ X    (one row per block; X-row loads coalesced, A row scalar)
__global__ void k_newt_T_r16(const float* __restrict__ A, const float* __restrict__ X,
                             float* __restrict__ T) {
  int i = blockIdx.x, j = threadIdx.x;
  const float* arow = &A[(size_t)i * kD];
  float s0 = 0.f, s1 = 0.f, s2 = 0.f, s3 = 0.f;
#pragma unroll 4
  for (int k = 0; k < kD; k += 4) {
    s0 = fmaf(arow[k + 0], X[(size_t)(k + 0) * kD + j], s0);
    s1 = fmaf(arow[k + 1], X[(size_t)(k + 1) * kD + j], s1);
    s2 = fmaf(arow[k + 2], X[(size_t)(k + 2) * kD + j], s2);
    s3 = fmaf(arow[k + 3], X[(size_t)(k + 3) * kD + j], s3);
  }
  float s = (s0 + s1) + (s2 + s3);
  T[(size_t)i * kD + j] = (i == j ? 2.0f : 0.0f) - s;
}

// Xn = X @ T
__global__ void k_newt_X_r16(const float* __restrict__ X, const float* __restrict__ T,
                             float* __restrict__ Xn) {
  int i = blockIdx.x, j = threadIdx.x;
  const float* xrow = &X[(size_t)i * kD];
  float s0 = 0.f, s1 = 0.f, s2 = 0.f, s3 = 0.f;
#pragma unroll 4
  for (int k = 0; k < kD; k += 4) {
    s0 = fmaf(xrow[k + 0], T[(size_t)(k + 0) * kD + j], s0);
    s1 = fmaf(xrow[k + 1], T[(size_t)(k + 1) * kD + j], s1);
    s2 = fmaf(xrow[k + 2], T[(size_t)(k + 2) * kD + j], s2);
    s3 = fmaf(xrow[k + 3], T[(size_t)(k + 3) * kD + j], s3);
  }
  Xn[(size_t)i * kD + j] = (s0 + s1) + (s2 + s3);
}

// G = (Q - mu) @ M
__global__ void k_G_r16(const float* __restrict__ Q, const float* __restrict__ mu,
                        const float* __restrict__ M, float* __restrict__ G) {
  __shared__ alignas(16) float As[16][68];
  __shared__ alignas(16) float Bs[16][68];
  int t = threadIdx.x, tx = t & 15, ty = t >> 4;
  int nb = blockIdx.x * 64;
  int mb = blockIdx.y * 64;
  float acc[4][4] = {};
  for (int k0 = 0; k0 < 256; k0 += 16) {
    __syncthreads();
    {
      int kk = t & 15, m0 = t >> 4;
      float muk = mu[k0 + kk];
#pragma unroll
      for (int p = 0; p < 4; ++p) {
        int m = m0 + p * 16;
        As[kk][m] = Q[(size_t)(mb + m) * kD + k0 + kk] - muk;
      }
      int j = t & 63, kr0 = t >> 6;
#pragma unroll
      for (int p = 0; p < 4; ++p) {
        int kr = kr0 + p * 4;
        Bs[kr][j] = M[(size_t)(k0 + kr) * kD + nb + j];
      }
    }
    __syncthreads();
#pragma unroll
    for (int k = 0; k < 16; ++k) {
      float4 a = *(const float4*)&As[k][ty * 4];
      float4 b = *(const float4*)&Bs[k][tx * 4];
      fma16(acc, a, b);
    }
  }
#pragma unroll
  for (int r = 0; r < 4; ++r) {
    int gi = mb + ty * 4 + r;
    float4 o = {acc[r][0], acc[r][1], acc[r][2], acc[r][3]};
    *(float4*)&G[(size_t)gi * kD + nb + tx * 4] = o;
  }
}

// q2p[i] = G_i . (Q_i + mu)
__global__ void k_q2p_r16(const float* __restrict__ G, const float* __restrict__ Q,
                          const float* __restrict__ mu, float* __restrict__ q2p) {
  int w = threadIdx.x >> 6, lane = threadIdx.x & 63;
  int row = blockIdx.x * 4 + w;
  float4 g = *(const float4*)&G[(size_t)row * kD + lane * 4];
  float4 q = *(const float4*)&Q[(size_t)row * kD + lane * 4];
  float4 m = *(const float4*)&mu[lane * 4];
  float ss = waveReduceSum(g.x*(q.x+m.x) + g.y*(q.y+m.y) + g.z*(q.z+m.z) + g.w*(q.w+m.w));
  if (lane == 0) q2p[row] = ss;
}

// s2[j] = (S_j - mu) M (S_j - mu), per 64-row chunk
__global__ void k_s2_r16(const float* __restrict__ S, const float* __restrict__ mu,
                         const float* __restrict__ M, float* __restrict__ s2) {
  __shared__ alignas(16) float As[16][68];
  __shared__ alignas(16) float Bs[16][68];
  __shared__ float red[64][17];
  int t = threadIdx.x, tx = t & 15, ty = t >> 4;
  int mb = blockIdx.x * 64;
  float partial[4] = {0.f, 0.f, 0.f, 0.f};
  for (int ntile = 0; ntile < 4; ++ntile) {
    int nb = ntile * 64;
    float acc[4][4] = {};
    for (int k0 = 0; k0 < 256; k0 += 16) {
      __syncthreads();
      {
        int kk = t & 15, m0 = t >> 4;
        float muk = mu[k0 + kk];
#pragma unroll
        for (int p = 0; p < 4; ++p) {
          int m = m0 + p * 16;
          As[kk][m] = S[(size_t)(mb + m) * kD + k0 + kk] - muk;
        }
        int j = t & 63, kr0 = t >> 6;
#pragma unroll
        for (int p = 0; p < 4; ++p) {
          int kr = kr0 + p * 4;
          Bs[kr][j] = M[(size_t)(k0 + kr) * kD + nb + j];
        }
      }
      __syncthreads();
#pragma unroll
      for (int k = 0; k < 16; ++k) {
        float4 a = *(const float4*)&As[k][ty * 4];
        float4 b = *(const float4*)&Bs[k][tx * 4];
        fma16(acc, a, b);
      }
    }
#pragma unroll
    for (int r = 0; r < 4; ++r) {
      int gi = mb + ty * 4 + r;
#pragma unroll
      for (int c = 0; c < 4; ++c) {
        int gj = nb + tx * 4 + c;
        partial[r] += acc[r][c] * (S[(size_t)gi * kD + gj] - mu[gj]);
      }
    }
  }
  __syncthreads();
#pragma unroll
  for (int r = 0; r < 4; ++r) red[ty * 4 + r][tx] = partial[r];
  __syncthreads();
  if (t < 64) {
    float s = 0.f;
#pragma unroll
    for (int x = 0; x < 16; ++x) s += red[t][x];
    s2[mb + t] = s;
  }
}

// GEMM-tiled sampled-median histogram
__global__ void k_median_r16(const float* __restrict__ G, const float* __restrict__ S,
                             const float* __restrict__ q2p, const float* __restrict__ s2,
                             unsigned int* __restrict__ hist, float* __restrict__ ssum) {
  __shared__ alignas(16) float As[16][68];
  __shared__ alignas(16) float Bs[16][68];
  __shared__ unsigned int h[2048];
  __shared__ float fred[4];
  int t = threadIdx.x, tx = t & 15, ty = t >> 4;
  int stile = blockIdx.x, qtile = blockIdx.y;
  for (int i = t; i < 2048; i += 256) h[i] = 0u;

  float acc[4][4] = {};
  for (int k0 = 0; k0 < 256; k0 += 16) {
    __syncthreads();
    {
      int kk = t & 15, m0 = t >> 4;
#pragma unroll
      for (int p = 0; p < 4; ++p) {
        int m = m0 + p * 16;
        As[kk][m] = G[(size_t)((qtile * 64 + m) * 8) * kD + k0 + kk];
        Bs[kk][m] = S[(size_t)((stile * 64 + m) * 8) * kD + k0 + kk];
      }
    }
    __syncthreads();
#pragma unroll
    for (int k = 0; k < 16; ++k) {
      float4 a = *(const float4*)&As[k][ty * 4];
      float4 b = *(const float4*)&Bs[k][tx * 4];
      fma16(acc, a, b);
    }
  }
  float fsum = 0.f;
#pragma unroll
  for (int r = 0; r < 4; ++r) {
    int qi = (qtile * 64 + ty * 4 + r) * 8;
    float q2v = q2p[qi];
#pragma unroll
    for (int c = 0; c < 4; ++c) {
      int sj = (stile * 64 + tx * 4 + c) * 8;
      float d2 = fmaxf(q2v + s2[sj] - 2.0f * acc[r][c], 0.0f);
      fsum += d2;
      int bin = (int)(d2 * 2.0f);
      bin = bin > 2047 ? 2047 : bin;
      atomicAdd(&h[bin], 1u);
    }
  }
  float wsum = waveReduceSum(fsum);
  if ((t & 63) == 0) fred[t >> 6] = wsum;
  __syncthreads();
  if (t == 0) atomicAdd(ssum, fred[0] + fred[1] + fred[2] + fred[3]);
  for (int i = t; i < 2048; i += 256)
    if (h[i]) atomicAdd(&hist[i], h[i]);
}

// Parallel median + gamma: 256 threads x 8 bins, LDS scan.
__global__ void k_gamma_r16(const unsigned int* __restrict__ hist,
                            const float* __restrict__ ssum, float* __restrict__ gptr) {
  __shared__ unsigned int ps[256];
  __shared__ float v0s, v1s;
  int t = threadIdx.x;
  unsigned int mine[8];
  unsigned int c = 0;
#pragma unroll
  for (int j = 0; j < 8; ++j) { mine[j] = hist[t * 8 + j]; c += mine[j]; }
  ps[t] = c;
  __syncthreads();
  // Hillis-Steele inclusive scan
  for (int off = 1; off < 256; off <<= 1) {
    unsigned int v = (t >= off) ? ps[t - off] : 0u;
    __syncthreads();
    ps[t] += v;
    __syncthreads();
  }
  unsigned int total = ps[255];
  unsigned int before = ps[t] - c;      // exclusive prefix for my 8 bins
  if (t == 0) { v0s = 0.f; v1s = 0.f; }
  __syncthreads();
  unsigned int rr0 = (total - 1) / 2, rr1 = total / 2;
  unsigned int cum = before;
#pragma unroll
  for (int j = 0; j < 8; ++j) {
    unsigned int cc = mine[j];
    if (cc > 0) {
      int bin = t * 8 + j;
      if (cum <= rr0 && rr0 < cum + cc) {
        float frac = (float)(rr0 - cum) + 0.5f;
        v0s = ((float)bin + frac / (float)cc) * 0.5f;
      }
      if (cum <= rr1 && rr1 < cum + cc) {
        float frac = (float)(rr1 - cum) + 0.5f;
        v1s = ((float)bin + frac / (float)cc) * 0.5f;
      }
    }
    cum += cc;
  }
  __syncthreads();
  if (t == 0) {
    float med = 0.5f * (v0s + v1s);
    float mean = (total > 0) ? (ssum[0] / (float)total) : 1.0f;
    float g = (med > 0.f) ? 1.0f / (med + 1e-6f) : 1.0f / (mean + 1e-6f);
    gptr[0] = g;
  }
}

// MAIN (MFMA, swizzled operands): grid (128 q-tiles, 16 s-chunks).
__global__ void PrototypicalHead_6210522710389_kernel(
    const unsigned short* __restrict__ Gh, const unsigned short* __restrict__ Sh,
    const float* __restrict__ q2p, const float* __restrict__ s2,
    const float* __restrict__ svals, const float* __restrict__ gptr,
    float* __restrict__ part) {
  int t = threadIdx.x;
  int w = t >> 6, lane = t & 63;
  int l15 = lane & 15, quad = lane >> 4;
  int qt = blockIdx.x, sc = blockIdx.y;
  int qbase = qt * 64;
  float gamma = gptr[0];

  size_t agrp = (size_t)(qt * 4 + w) * 4096;
  bf16x8 afrag[8];
#pragma unroll
  for (int ks = 0; ks < 8; ++ks)
    afrag[ks] = *(const bf16x8*)&Gh[agrp + (size_t)ks * 512 + (size_t)lane * 8];

  float q2v[4];
#pragma unroll
  for (int r = 0; r < 4; ++r) q2v[r] = q2p[qbase + w * 16 + quad * 4 + r];

  float dAcc[4] = {0.f, 0.f, 0.f, 0.f}, nAcc[4] = {0.f, 0.f, 0.f, 0.f};

  for (int st = 0; st < 16; ++st) {
    int sbase = sc * 1024 + st * 64;
    int sgrp = sbase >> 4;
    f32x4 acc0 = {0.f, 0.f, 0.f, 0.f};
    f32x4 acc1 = {0.f, 0.f, 0.f, 0.f};
    f32x4 acc2 = {0.f, 0.f, 0.f, 0.f};
    f32x4 acc3 = {0.f, 0.f, 0.f, 0.f};
    const unsigned short* B0 = &Sh[(size_t)(sgrp + 0) * 4096 + (size_t)lane * 8];
    const unsigned short* B1 = &Sh[(size_t)(sgrp + 1) * 4096 + (size_t)lane * 8];
    const unsigned short* B2 = &Sh[(size_t)(sgrp + 2) * 4096 + (size_t)lane * 8];
    const unsigned short* B3 = &Sh[(size_t)(sgrp + 3) * 4096 + (size_t)lane * 8];
#pragma unroll
    for (int ks = 0; ks < 8; ++ks) {
      bf16x8 f0 = *(const bf16x8*)(B0 + ks * 512);
      bf16x8 f1 = *(const bf16x8*)(B1 + ks * 512);
      bf16x8 f2 = *(const bf16x8*)(B2 + ks * 512);
      bf16x8 f3 = *(const bf16x8*)(B3 + ks * 512);
      acc0 = __builtin_amdgcn_mfma_f32_16x16x32_bf16(afrag[ks], f0, acc0, 0, 0, 0);
      acc1 = __builtin_amdgcn_mfma_f32_16x16x32_bf16(afrag[ks], f1, acc1, 0, 0, 0);
      acc2 = __builtin_amdgcn_mfma_f32_16x16x32_bf16(afrag[ks], f2, acc2, 0, 0, 0);
      acc3 = __builtin_amdgcn_mfma_f32_16x16x32_bf16(afrag[ks], f3, acc3, 0, 0, 0);
    }
#pragma unroll
    for (int nt = 0; nt < 4; ++nt) {
      f32x4 a = (nt == 0) ? acc0 : (nt == 1) ? acc1 : (nt == 2) ? acc2 : acc3;
      int scol = sbase + nt * 16 + l15;
      float s2v = s2[scol];
      float sv = svals[scol];
#pragma unroll
      for (int r = 0; r < 4; ++r) {
        float d2 = fmaxf(q2v[r] + s2v - 2.0f * a[r], 0.0f);
        float e = __expf(-gamma * d2);
        dAcc[r] += e;
        nAcc[r] += e * sv;
      }
    }
  }
#pragma unroll
  for (int off = 8; off >= 1; off >>= 1) {
#pragma unroll
    for (int r = 0; r < 4; ++r) {
      dAcc[r] += __shfl_xor(dAcc[r], off);
      nAcc[r] += __shfl_xor(nAcc[r], off);
    }
  }
  if (l15 == 0) {
#pragma unroll
    for (int r = 0; r < 4; ++r) {
      size_t q = (size_t)qbase + w * 16 + quad * 4 + r;
      part[(q * 16 + sc) * 2 + 0] = dAcc[r];
      part[(q * 16 + sc) * 2 + 1] = nAcc[r];
    }
  }
}

__global__ void k_final_r16(const float* __restrict__ part, float* __restrict__ out1) {
  int q = blockIdx.x * 256 + threadIdx.x;
  const float* p = part + (size_t)q * 32;
  float d = 0.f, n = 0.f;
#pragma unroll
  for (int i = 0; i < 16; ++i) { d += p[2 * i]; n += p[2 * i + 1]; }
  out1[q] = n / d;
}

extern "C" void kernel_launch(void* const* d_in, const int* in_sizes, int n_in,
                              void* d_out, int out_size, void* d_ws, size_t ws_size,
                              hipStream_t stream) {
  (void)in_sizes; (void)n_in; (void)out_size; (void)ws_size;
  const float* SF = (const float*)d_in[0];   // fp32
  const int*   SL = (const int*)d_in[1];     // int32
  const float* SV = (const float*)d_in[2];   // fp32
  const float* QF = (const float*)d_in[3];   // fp32

  float* ws = (float*)d_ws;
  float* psum  = ws + OFF_PSUM;
  float* pcnt  = ws + OFF_PCNT;
  float* musum = ws + OFF_MUSUM;
  float* xtx   = ws + OFF_XTX;
  unsigned int* hist = (unsigned int*)(ws + OFF_HIST);
  float* ssum  = ws + OFF_SSUM;
  float* protos= ws + OFF_PROTO;
  float* mu    = ws + OFF_MU;
  float* cov   = ws + OFF_COV;
  float* rows  = ws + OFF_ROWS;
  float* cptr  = ws + OFF_C;
  float* gptr  = ws + OFF_C + 1;
  float* X1 = ws + OFF_Y;  float* T = ws + OFF_T;  float* X2 = ws + OFF_Y2;
  float* s2 = ws + OFF_S2; float* q2p = ws + OFF_Q2P;
  float* part = ws + OFF_PART;
  float* G = ws + OFF_G;
  unsigned short* Sh = (unsigned short*)(ws + OFF_SH);
  unsigned short* Gh = (unsigned short*)(ws + OFF_GH);

  float* out0 = (float*)d_out;                   // f32 log_probs [8192 x 64]
  float* out1 = out0 + (size_t)kNQ * kC;         // f32 predictions [8192]

  k_zero_r16<<<(int)((ZERO_FLOATS + 255) / 256), 256, 0, stream>>>(ws);

  // swizzled bf16 copy of support features
  k_swz_r16<<<kNS / 16, 256, 0, stream>>>(SF, Sh);

  // classification
  k_proto_accum_r16<<<kNS / 4, 256, 0, stream>>>(SF, SL, psum, pcnt);
  k_proto_fin_r16<<<kC, 64, 0, stream>>>(psum, pcnt, protos);
  k_logits_r16<<<kNQ, 256, 0, stream>>>(QF, protos, out0);

  // regression: mean, cov
  k_colsum_r16<<<kNS / 64, 256, 0, stream>>>(SF, musum);
  k_mufin_r16<<<1, 256, 0, stream>>>(musum, mu);
  k_xtx_r16<<<dim3(16, 16), 256, 0, stream>>>(SF, xtx);
  k_cov_r16<<<256, 256, 0, stream>>>(xtx, mu, cov);

  // Newton matrix inverse: X <- X (2I - cov X), X0 = I/c, 6 iterations
  k_rowabs_r16<<<256, 64, 0, stream>>>(cov, rows);
  k_cnorm_r16<<<1, 64, 0, stream>>>(rows, cptr);
  k_newt_init_r16<<<256, 256, 0, stream>>>(cptr, X1);
  float *Xc = X1, *Xn = X2;
  for (int it = 0; it < 6; ++it) {
    k_newt_T_r16<<<256, 256, 0, stream>>>(cov, Xc, T);
    k_newt_X_r16<<<256, 256, 0, stream>>>(Xc, T, Xn);
    float* tmp = Xc; Xc = Xn; Xn = tmp;
  }
  float* M = Xc;   // cov^-1

  // G = (Q - mu) @ M, swizzled bf16 copy, scalar row terms
  k_G_r16<<<dim3(4, kNQ / 64), 256, 0, stream>>>(QF, mu, M, G);
  k_swz_r16<<<kNQ / 16, 256, 0, stream>>>(G, Gh);
  k_q2p_r16<<<kNQ / 4, 256, 0, stream>>>(G, QF, mu, q2p);
  k_s2_r16<<<kNS / 64, 256, 0, stream>>>(SF, mu, M, s2);

  // sampled median -> gamma (parallel)
  k_median_r16<<<dim3(32, 16), 256, 0, stream>>>(G, SF, q2p, s2, hist, ssum);
  k_gamma_r16<<<1, 256, 0, stream>>>(hist, ssum, gptr);

  // MFMA fused cdist^2 + softmax numer/denom, then finalize
  PrototypicalHead_6210522710389_kernel<<<dim3(128, 16), 256, 0, stream>>>(
      Gh, Sh, q2p, s2, SV, gptr, part);
  k_final_r16<<<kNQ / 256, 256, 0, stream>>>(part, out1);
}